// Round 3
// baseline (612.416 us; speedup 1.0000x reference)
//
#include <hip/hip_runtime.h>
#include <hip/hip_cooperative_groups.h>
#include <math.h>

namespace cg = cooperative_groups;

#define DMODEL 256
#define NH 8
#define DH 32
#define NEG_INF -1e30f

// ======================================================================
// Shared GEMM compute: 128 threads, 32x64 tile, micro 4x4, K=256
// ======================================================================
__device__ __forceinline__ void gemm_compute(const float (*__restrict__ As)[36],
                                             const float (*__restrict__ Bs)[64],
                                             float acc[4][4])
{
  int tid = threadIdx.x;
  int tx = tid & 15, ty = tid >> 4;     // tx: col/4 (0..15), ty: row/4 (0..7)
#pragma unroll 8
  for (int k = 0; k < 256; ++k) {
    float4 a  = *(const float4*)&As[k][ty * 4];
    float4 bv = *(const float4*)&Bs[k][tx * 4];
    acc[0][0] = fmaf(a.x, bv.x, acc[0][0]); acc[0][1] = fmaf(a.x, bv.y, acc[0][1]);
    acc[0][2] = fmaf(a.x, bv.z, acc[0][2]); acc[0][3] = fmaf(a.x, bv.w, acc[0][3]);
    acc[1][0] = fmaf(a.y, bv.x, acc[1][0]); acc[1][1] = fmaf(a.y, bv.y, acc[1][1]);
    acc[1][2] = fmaf(a.y, bv.z, acc[1][2]); acc[1][3] = fmaf(a.y, bv.w, acc[1][3]);
    acc[2][0] = fmaf(a.z, bv.x, acc[2][0]); acc[2][1] = fmaf(a.z, bv.y, acc[2][1]);
    acc[2][2] = fmaf(a.z, bv.z, acc[2][2]); acc[2][3] = fmaf(a.z, bv.w, acc[2][3]);
    acc[3][0] = fmaf(a.w, bv.x, acc[3][0]); acc[3][1] = fmaf(a.w, bv.y, acc[3][1]);
    acc[3][2] = fmaf(a.w, bv.z, acc[3][2]); acc[3][3] = fmaf(a.w, bv.w, acc[3][3]);
  }
}

// ---------------- 256-thread staging (megakernel) ----------------
__device__ __forceinline__ void stageB_256(const float* __restrict__ Bw, int ldb, int n0,
                                           float (*__restrict__ Bs)[64])
{
  int tid = threadIdx.x;
#pragma unroll
  for (int i = 0; i < 16; ++i) {
    int idx = tid + 256 * i;            // 0..4095 float4s
    int k = idx >> 4, c = (idx & 15) << 2;
    *(float4*)&Bs[k][c] = *(const float4*)(Bw + (size_t)k * ldb + n0 + c);
  }
}

__device__ __forceinline__ void stageA_copy_256(const float* __restrict__ A, int lda,
                                                int m0, int kbeg,
                                                float (*__restrict__ As)[36])
{
  int tid = threadIdx.x;
  int r = tid >> 3, p = tid & 7;        // row 0..31, eighth 0..7
  const float* row = A + (size_t)(m0 + r) * lda + kbeg + p * 32;
#pragma unroll
  for (int j = 0; j < 8; ++j) {
    float4 v = *(const float4*)(row + j * 4);
    int k = p * 32 + j * 4;
    As[k + 0][r] = v.x; As[k + 1][r] = v.y; As[k + 2][r] = v.z; As[k + 3][r] = v.w;
  }
}

__device__ __forceinline__ void stageA_ln_256(const float* __restrict__ Xsrc, int m0,
                                              const float* __restrict__ g,
                                              const float* __restrict__ b,
                                              float (*__restrict__ As)[36])
{
  int tid = threadIdx.x;
  int r = tid >> 3, p = tid & 7;
  const float* row = Xsrc + (size_t)(m0 + r) * DMODEL + p * 32;
  float4 v[8];
  float s = 0.f, ss = 0.f;
#pragma unroll
  for (int j = 0; j < 8; ++j) {
    v[j] = *(const float4*)(row + j * 4);
    s  += v[j].x + v[j].y + v[j].z + v[j].w;
    ss += v[j].x * v[j].x + v[j].y * v[j].y + v[j].z * v[j].z + v[j].w * v[j].w;
  }
  s  += __shfl_xor(s, 1);  s  += __shfl_xor(s, 2);  s  += __shfl_xor(s, 4);
  ss += __shfl_xor(ss, 1); ss += __shfl_xor(ss, 2); ss += __shfl_xor(ss, 4);
  float mean = s * (1.0f / 256.0f);
  float var  = ss * (1.0f / 256.0f) - mean * mean;
  float rstd = rsqrtf(var + 1e-5f);
#pragma unroll
  for (int j = 0; j < 8; ++j) {
    float4 gg = *(const float4*)(g + p * 32 + j * 4);
    float4 bb = *(const float4*)(b + p * 32 + j * 4);
    int k = p * 32 + j * 4;
    As[k + 0][r] = (v[j].x - mean) * rstd * gg.x + bb.x;
    As[k + 1][r] = (v[j].y - mean) * rstd * gg.y + bb.y;
    As[k + 2][r] = (v[j].z - mean) * rstd * gg.z + bb.z;
    As[k + 3][r] = (v[j].w - mean) * rstd * gg.w + bb.w;
  }
}

// ======================================================================
// Cooperative megakernel: 256 blocks x 256 threads, 9 grid syncs.
// Phase bodies identical to the verified split kernels.
// ======================================================================
struct MegaParams {
  const float* src; const float* tgt; const float* rpe;
  const int* smask; const int* tmask;
  const float* ln1g; const float* ln1b; const float* lntg; const float* lntb;
  const float* ln2g; const float* ln2b;
  const float* wq; const float* bq; const float* wk; const float* bk;
  const float* wv; const float* bv; const float* wo; const float* bo;
  const float* wr; const float* br; const float* w1; const float* b1;
  const float* w2; const float* b2;
  float* out; float* Qb; float* Kb; float* Vb; float* AO; float* X; float* SRC1; float* H1;
};

__global__ __launch_bounds__(256) void mega_kernel(MegaParams p)
{
  cg::grid_group grid = cg::this_grid();
  __shared__ __align__(16) float smem[25600];   // 102.4 KB union
  float (*As)[36]  = reinterpret_cast<float (*)[36]>(smem);          // 9216 floats
  float (*Bs)[64]  = reinterpret_cast<float (*)[64]>(smem + 9216);   // 16384 floats
  float (*Ks)[32]  = reinterpret_cast<float (*)[32]>(smem);          // 8192
  float (*Vt)[260] = reinterpret_cast<float (*)[260]>(smem + 8192);  // 8320
  float (*ps)[256] = reinterpret_cast<float (*)[256]>(smem + 16512); // 1024
  float (*qs)[32]  = reinterpret_cast<float (*)[32]>(smem + 17536);  // 512
  float (*wks)[32] = reinterpret_cast<float (*)[32]>(smem + 18048);  // 160
  float (*wvs)[32] = reinterpret_cast<float (*)[32]>(smem + 18208);  // 160
  int bid = blockIdx.x, tid = threadIdx.x;

  for (int l = 0; l < 2; ++l) {
    const float* srcin = l ? p.SRC1 : p.src;
    float* outb = l ? p.out : p.SRC1;
    const float* wq = p.wq + l * 65536;  const float* bq = p.bq + l * 256;
    const float* wk = p.wk + l * 65536;  const float* bk = p.bk + l * 256;
    const float* wv = p.wv + l * 65536;  const float* bv = p.bv + l * 256;
    const float* wo = p.wo + l * 65536;  const float* bo = p.bo + l * 256;
    const float* wr = p.wr + l * 2048;   const float* br = p.br + l * 512;
    const float* w1 = p.w1 + l * 262144; const float* b1 = p.b1 + l * 1024;
    const float* w2 = p.w2 + l * 262144; const float* b2 = p.b2 + l * 256;
    const float* ln1g = p.ln1g + l * 256; const float* ln1b = p.ln1b + l * 256;
    const float* lntg = p.lntg + l * 256; const float* lntb = p.lntb + l * 256;
    const float* ln2g = p.ln2g + l * 256; const float* ln2b = p.ln2b + l * 256;

    // ===== phase 1: QKV (192 tasks) =====
    if (bid < 192) {
      int x = bid & 3, y = (bid >> 2) & 15, z = bid >> 6;
      int m0 = y * 32, n0 = x * 64;
      const float* Bw = (z == 0) ? wq : (z == 1) ? wk : wv;
      stageB_256(Bw, DMODEL, n0, Bs);
      if (z == 0) stageA_ln_256(srcin, m0, ln1g, ln1b, As);
      else        stageA_ln_256(p.tgt, m0, lntg, lntb, As);
      __syncthreads();
      if (tid < 128) {
        float acc[4][4] = {};
        gemm_compute(As, Bs, acc);
        const float* bias = (z == 0) ? bq : (z == 1) ? bk : bv;
        int tx = tid & 15, ty = tid >> 4;
        int c0 = n0 + tx * 4;
        float4 bias4 = *(const float4*)(bias + c0);
        const float scale = 0.1767766952966369f;  // 1/sqrt(32)
#pragma unroll
        for (int i = 0; i < 4; ++i) {
          int m = m0 + ty * 4 + i;
          float4 r;
          r.x = acc[i][0] + bias4.x;
          r.y = acc[i][1] + bias4.y;
          r.z = acc[i][2] + bias4.z;
          r.w = acc[i][3] + bias4.w;
          if (z == 0) {
            r.x *= scale; r.y *= scale; r.z *= scale; r.w *= scale;
            *(float4*)&p.Qb[m * DMODEL + c0] = r;
          } else {
            int b_ = m >> 8, t = m & 255, h = c0 >> 5, d0 = c0 & 31;
            float* dst = ((z == 1) ? p.Kb : p.Vb) + (size_t)(b_ * NH + h) * 8192 + t * DH + d0;
            *(float4*)dst = r;
          }
        }
      }
    }
    grid.sync();

    // ===== phase 2: attention (256 tasks) =====
    {
      int ab = bid >> 7, h = (bid >> 4) & 7, s0 = (bid & 15) << 4;
      const float* Kp = p.Kb + (size_t)(ab * NH + h) * 8192;
      const float* Vp = p.Vb + (size_t)(ab * NH + h) * 8192;
      {
        int t = tid;
        const float4* kr = (const float4*)(Kp + t * DH);
        const float4* vr = (const float4*)(Vp + t * DH);
        int sw = t & 7;
#pragma unroll
        for (int c = 0; c < 8; ++c) {
          float4 k4 = kr[c];
          *(float4*)&Ks[t][(c ^ sw) * 4] = k4;
        }
#pragma unroll
        for (int c = 0; c < 8; ++c) {
          float4 v4 = vr[c];
          Vt[c*4+0][t] = v4.x; Vt[c*4+1][t] = v4.y; Vt[c*4+2][t] = v4.z; Vt[c*4+3][t] = v4.w;
        }
      }
      if (tid < 160) {
        int j = tid >> 5, d = tid & 31;
        wks[j][d] = (j < 4) ? wr[j * 512 + h * DH + d]       : br[h * DH + d];
        wvs[j][d] = (j < 4) ? wr[j * 512 + 256 + h * DH + d] : br[256 + h * DH + d];
      }
      if (tid >= 128) {
        int u = tid - 128;
        int rr_ = u >> 3, cc = u & 7;
        *(float4*)&qs[rr_][cc*4] =
            *(const float4*)&p.Qb[(ab * 256 + s0 + rr_) * DMODEL + h * DH + cc * 4];
      }
      __syncthreads();

      int w = tid >> 6, lane = tid & 63;
      int msk[4];
#pragma unroll
      for (int it = 0; it < 4; ++it) msk[it] = p.tmask[ab * 256 + it * 64 + lane];

      for (int i = 0; i < 4; ++i) {
        int sl = w * 4 + i;
        int s = s0 + sl;
        float4 q4[8];
#pragma unroll
        for (int c = 0; c < 8; ++c) q4[c] = *(const float4*)&qs[sl][c * 4];
        float qw[4]; float qbr = 0.0f;
#pragma unroll
        for (int j = 0; j < 4; ++j) {
          float t0 = 0;
#pragma unroll
          for (int c = 0; c < 8; ++c) {
            float4 wv4 = *(const float4*)&wks[j][c * 4];
            t0 += q4[c].x*wv4.x + q4[c].y*wv4.y + q4[c].z*wv4.z + q4[c].w*wv4.w;
          }
          qw[j] = t0;
        }
#pragma unroll
        for (int c = 0; c < 8; ++c) {
          float4 wv4 = *(const float4*)&wks[4][c * 4];
          qbr += q4[c].x*wv4.x + q4[c].y*wv4.y + q4[c].z*wv4.z + q4[c].w*wv4.w;
        }
        const float4* rp4 = (const float4*)(p.rpe + (size_t)(ab * 256 + s) * 1024);
        float sc[4]; float4 rr[4];
#pragma unroll
        for (int it = 0; it < 4; ++it) {
          int t = it * 64 + lane;
          int sw = t & 7;
          float sv = 0;
#pragma unroll
          for (int c = 0; c < 8; ++c) {
            float4 k4 = *(const float4*)&Ks[t][(c ^ sw) * 4];
            sv = fmaf(q4[c].x, k4.x, sv); sv = fmaf(q4[c].y, k4.y, sv);
            sv = fmaf(q4[c].z, k4.z, sv); sv = fmaf(q4[c].w, k4.w, sv);
          }
          float4 rv = rp4[t];
          rr[it] = rv;
          sv += rv.x*qw[0] + rv.y*qw[1] + rv.z*qw[2] + rv.w*qw[3] + qbr;
          if (msk[it] != 0) sv = NEG_INF;
          sc[it] = sv;
        }
        float mval = fmaxf(fmaxf(sc[0], sc[1]), fmaxf(sc[2], sc[3]));
#pragma unroll
        for (int off = 32; off >= 1; off >>= 1) mval = fmaxf(mval, __shfl_xor(mval, off));
        float pr[4], lsum = 0;
#pragma unroll
        for (int it = 0; it < 4; ++it) { pr[it] = __expf(sc[it] - mval); lsum += pr[it]; }
        float wj0 = 0, wj1 = 0, wj2 = 0, wj3 = 0;
#pragma unroll
        for (int it = 0; it < 4; ++it) {
          wj0 = fmaf(pr[it], rr[it].x, wj0);
          wj1 = fmaf(pr[it], rr[it].y, wj1);
          wj2 = fmaf(pr[it], rr[it].z, wj2);
          wj3 = fmaf(pr[it], rr[it].w, wj3);
        }
#pragma unroll
        for (int off = 32; off >= 1; off >>= 1) {
          lsum += __shfl_xor(lsum, off);
          wj0 += __shfl_xor(wj0, off);
          wj1 += __shfl_xor(wj1, off);
          wj2 += __shfl_xor(wj2, off);
          wj3 += __shfl_xor(wj3, off);
        }
#pragma unroll
        for (int it = 0; it < 4; ++it) ps[w][it * 64 + lane] = pr[it];
        int g = lane >> 5, d = lane & 31;
        float o = 0;
#pragma unroll
        for (int n = 0; n < 32; ++n) {
          int t = g * 128 + n * 4;
          float4 p4 = *(const float4*)&ps[w][t];
          float4 v4 = *(const float4*)&Vt[d][t];
          o += p4.x*v4.x + p4.y*v4.y + p4.z*v4.z + p4.w*v4.w;
        }
        o += __shfl_xor(o, 32);
        float corr = wj0 * wvs[0][d] + wj1 * wvs[1][d] + wj2 * wvs[2][d] + wj3 * wvs[3][d];
        float oval = (o + corr) / lsum + wvs[4][d];
        if (lane < 32) p.AO[(ab * 256 + s) * DMODEL + h * DH + d] = oval;
      }
    }
    grid.sync();

    // ===== phase 3: wo + residual (64 tasks) =====
    if (bid < 64) {
      int x = bid & 3, y = bid >> 2;
      int m0 = y * 32, n0 = x * 64;
      stageB_256(wo, DMODEL, n0, Bs);
      stageA_copy_256(p.AO, DMODEL, m0, 0, As);
      __syncthreads();
      if (tid < 128) {
        float acc[4][4] = {};
        gemm_compute(As, Bs, acc);
        int tx = tid & 15, ty = tid >> 4;
        int c0 = n0 + tx * 4;
        float4 bov = *(const float4*)(bo + c0);
#pragma unroll
        for (int i = 0; i < 4; ++i) {
          int m = m0 + ty * 4 + i;
          float4 sv = *(const float4*)(srcin + (size_t)m * DMODEL + c0);
          float4 r;
          r.x = sv.x + bov.x + acc[i][0];
          r.y = sv.y + bov.y + acc[i][1];
          r.z = sv.z + bov.z + acc[i][2];
          r.w = sv.w + bov.w + acc[i][3];
          *(float4*)&p.X[(size_t)m * DMODEL + c0] = r;
        }
      }
    }
    grid.sync();

    // ===== phase 4: FF1 + LN2 + ReLU; x==0 writes out-init (256 tasks) =====
    {
      int x = bid & 15, y = bid >> 4;
      int m0 = y * 32, n0 = x * 64;
      stageB_256(w1, 1024, n0, Bs);
      stageA_ln_256(p.X, m0, ln2g, ln2b, As);
      if (x == 0 && tid < 128) {
        int r = tid >> 2, pq = tid & 3;
        int m = m0 + r;
        float mm = (p.smask[m] != 0) ? 0.0f : 1.0f;
#pragma unroll
        for (int j = 0; j < 16; ++j) {
          float4 xv  = *(const float4*)(p.X + (size_t)m * DMODEL + pq * 64 + j * 4);
          float4 b2v = *(const float4*)(b2 + pq * 64 + j * 4);
          float4 o;
          o.x = mm * (xv.x + b2v.x); o.y = mm * (xv.y + b2v.y);
          o.z = mm * (xv.z + b2v.z); o.w = mm * (xv.w + b2v.w);
          *(float4*)(outb + (size_t)m * DMODEL + pq * 64 + j * 4) = o;
        }
      }
      __syncthreads();
      if (tid < 128) {
        float acc[4][4] = {};
        gemm_compute(As, Bs, acc);
        int tx = tid & 15, ty = tid >> 4;
        int c0 = n0 + tx * 4;
        float4 b1v = *(const float4*)(b1 + c0);
#pragma unroll
        for (int i = 0; i < 4; ++i) {
          int m = m0 + ty * 4 + i;
          float4 r;
          r.x = fmaxf(acc[i][0] + b1v.x, 0.0f);
          r.y = fmaxf(acc[i][1] + b1v.y, 0.0f);
          r.z = fmaxf(acc[i][2] + b1v.z, 0.0f);
          r.w = fmaxf(acc[i][3] + b1v.w, 0.0f);
          *(float4*)&p.H1[(size_t)m * 1024 + c0] = r;
        }
      }
    }
    grid.sync();

    // ===== phase 5: FF2 split-K=4, masked atomic accumulate (256 tasks) =====
    {
      int x = bid & 3, y = (bid >> 2) & 15, z = bid >> 6;
      int m0 = y * 32, n0 = x * 64;
      int kbeg = z * 256;
      stageB_256(w2 + (size_t)kbeg * DMODEL, DMODEL, n0, Bs);
      stageA_copy_256(p.H1, 1024, m0, kbeg, As);
      __syncthreads();
      if (tid < 128) {
        float acc[4][4] = {};
        gemm_compute(As, Bs, acc);
        int tx = tid & 15, ty = tid >> 4;
        int c0 = n0 + tx * 4;
#pragma unroll
        for (int i = 0; i < 4; ++i) {
          int m = m0 + ty * 4 + i;
          if (p.smask[m] == 0) {
            atomicAdd(&outb[(size_t)m * DMODEL + c0 + 0], acc[i][0]);
            atomicAdd(&outb[(size_t)m * DMODEL + c0 + 1], acc[i][1]);
            atomicAdd(&outb[(size_t)m * DMODEL + c0 + 2], acc[i][2]);
            atomicAdd(&outb[(size_t)m * DMODEL + c0 + 3], acc[i][3]);
          }
        }
      }
    }
    if (l == 0) grid.sync();
  }
}

// ======================================================================
// Fallback: verified round-2 split kernels (used if cooperative launch fails)
// ======================================================================
__device__ __forceinline__ void stage_B64(const float* __restrict__ Bw, int ldb, int n0,
                                          float (*__restrict__ Bs)[64])
{
  int tid = threadIdx.x;
#pragma unroll
  for (int i = 0; i < 32; ++i) {
    int idx = tid + 128 * i;
    int k = idx >> 4, c = (idx & 15) << 2;
    *(float4*)&Bs[k][c] = *(const float4*)(Bw + (size_t)k * ldb + n0 + c);
  }
}

__device__ __forceinline__ void stage_A_copy(const float* __restrict__ A, int lda,
                                             int m0, int kbeg,
                                             float (*__restrict__ As)[36])
{
  int tid = threadIdx.x;
  int r = tid >> 2, p = tid & 3;
  const float* row = A + (size_t)(m0 + r) * lda + kbeg + p * 64;
#pragma unroll
  for (int j = 0; j < 16; ++j) {
    float4 v = *(const float4*)(row + j * 4);
    int k = p * 64 + j * 4;
    As[k + 0][r] = v.x; As[k + 1][r] = v.y; As[k + 2][r] = v.z; As[k + 3][r] = v.w;
  }
}

__device__ __forceinline__ void stage_A_ln(const float* __restrict__ Xsrc, int m0,
                                           const float* __restrict__ g,
                                           const float* __restrict__ b,
                                           float (*__restrict__ As)[36])
{
  int tid = threadIdx.x;
  int r = tid >> 2, p = tid & 3;
  const float* row = Xsrc + (size_t)(m0 + r) * DMODEL + p * 64;
  float4 v[16];
  float s = 0.f, ss = 0.f;
#pragma unroll
  for (int j = 0; j < 16; ++j) {
    v[j] = *(const float4*)(row + j * 4);
    s  += v[j].x + v[j].y + v[j].z + v[j].w;
    ss += v[j].x * v[j].x + v[j].y * v[j].y + v[j].z * v[j].z + v[j].w * v[j].w;
  }
  s  += __shfl_xor(s, 1);  s  += __shfl_xor(s, 2);
  ss += __shfl_xor(ss, 1); ss += __shfl_xor(ss, 2);
  float mean = s * (1.0f / 256.0f);
  float var  = ss * (1.0f / 256.0f) - mean * mean;
  float rstd = rsqrtf(var + 1e-5f);
#pragma unroll
  for (int j = 0; j < 16; ++j) {
    float4 gg = *(const float4*)(g + p * 64 + j * 4);
    float4 bb = *(const float4*)(b + p * 64 + j * 4);
    int k = p * 64 + j * 4;
    As[k + 0][r] = (v[j].x - mean) * rstd * gg.x + bb.x;
    As[k + 1][r] = (v[j].y - mean) * rstd * gg.y + bb.y;
    As[k + 2][r] = (v[j].z - mean) * rstd * gg.z + bb.z;
    As[k + 3][r] = (v[j].w - mean) * rstd * gg.w + bb.w;
  }
}

__global__ __launch_bounds__(128) void qkv_kernel(
    const float* __restrict__ srcin, const float* __restrict__ tgt,
    const float* __restrict__ ln1g, const float* __restrict__ ln1b,
    const float* __restrict__ lntg, const float* __restrict__ lntb,
    const float* __restrict__ wq, const float* __restrict__ wk, const float* __restrict__ wv,
    const float* __restrict__ bq, const float* __restrict__ bk, const float* __restrict__ bv,
    float* __restrict__ Qb, float* __restrict__ Kb, float* __restrict__ Vb)
{
  __shared__ __align__(16) float As[256][36];
  __shared__ __align__(16) float Bs[256][64];
  int z = blockIdx.z;
  int m0 = blockIdx.y * 32, n0 = blockIdx.x * 64;
  const float* Bw = (z == 0) ? wq : (z == 1) ? wk : wv;
  stage_B64(Bw, DMODEL, n0, Bs);
  if (z == 0) stage_A_ln(srcin, m0, ln1g, ln1b, As);
  else        stage_A_ln(tgt,   m0, lntg, lntb, As);
  __syncthreads();
  float acc[4][4] = {};
  gemm_compute(As, Bs, acc);
  const float* bias = (z == 0) ? bq : (z == 1) ? bk : bv;
  int tid = threadIdx.x, tx = tid & 15, ty = tid >> 4;
  int c0 = n0 + tx * 4;
  float4 bias4 = *(const float4*)(bias + c0);
  const float scale = 0.1767766952966369f;
#pragma unroll
  for (int i = 0; i < 4; ++i) {
    int m = m0 + ty * 4 + i;
    float4 r;
    r.x = acc[i][0] + bias4.x;
    r.y = acc[i][1] + bias4.y;
    r.z = acc[i][2] + bias4.z;
    r.w = acc[i][3] + bias4.w;
    if (z == 0) {
      r.x *= scale; r.y *= scale; r.z *= scale; r.w *= scale;
      *(float4*)&Qb[m * DMODEL + c0] = r;
    } else {
      int b = m >> 8, t = m & 255, h = c0 >> 5, d0 = c0 & 31;
      float* dst = ((z == 1) ? Kb : Vb) + (size_t)(b * NH + h) * 8192 + t * DH + d0;
      *(float4*)dst = r;
    }
  }
}

__global__ __launch_bounds__(128) void wo_kernel(
    const float* __restrict__ AO, const float* __restrict__ wo,
    const float* __restrict__ srcin, const float* __restrict__ bo,
    float* __restrict__ X)
{
  __shared__ __align__(16) float As[256][36];
  __shared__ __align__(16) float Bs[256][64];
  int m0 = blockIdx.y * 32, n0 = blockIdx.x * 64;
  stage_B64(wo, DMODEL, n0, Bs);
  stage_A_copy(AO, DMODEL, m0, 0, As);
  __syncthreads();
  float acc[4][4] = {};
  gemm_compute(As, Bs, acc);
  int tid = threadIdx.x, tx = tid & 15, ty = tid >> 4;
  int c0 = n0 + tx * 4;
  float4 bov = *(const float4*)(bo + c0);
#pragma unroll
  for (int i = 0; i < 4; ++i) {
    int m = m0 + ty * 4 + i;
    float4 sv = *(const float4*)(srcin + (size_t)m * DMODEL + c0);
    float4 r;
    r.x = sv.x + bov.x + acc[i][0];
    r.y = sv.y + bov.y + acc[i][1];
    r.z = sv.z + bov.z + acc[i][2];
    r.w = sv.w + bov.w + acc[i][3];
    *(float4*)&X[(size_t)m * DMODEL + c0] = r;
  }
}

__global__ __launch_bounds__(128) void ff1_kernel(
    const float* __restrict__ X, const float* __restrict__ ln2g, const float* __restrict__ ln2b,
    const float* __restrict__ w1, const float* __restrict__ b1,
    const float* __restrict__ b2, const int* __restrict__ smask,
    float* __restrict__ H1, float* __restrict__ outb)
{
  __shared__ __align__(16) float As[256][36];
  __shared__ __align__(16) float Bs[256][64];
  int m0 = blockIdx.y * 32, n0 = blockIdx.x * 64;
  stage_B64(w1, 1024, n0, Bs);
  stage_A_ln(X, m0, ln2g, ln2b, As);
  if (blockIdx.x == 0) {
    int tid = threadIdx.x;
    int r = tid >> 2, p = tid & 3;
    int m = m0 + r;
    float mm = (smask[m] != 0) ? 0.0f : 1.0f;
#pragma unroll
    for (int j = 0; j < 16; ++j) {
      float4 xv  = *(const float4*)(X  + (size_t)m * DMODEL + p * 64 + j * 4);
      float4 b2v = *(const float4*)(b2 + p * 64 + j * 4);
      float4 o;
      o.x = mm * (xv.x + b2v.x); o.y = mm * (xv.y + b2v.y);
      o.z = mm * (xv.z + b2v.z); o.w = mm * (xv.w + b2v.w);
      *(float4*)(outb + (size_t)m * DMODEL + p * 64 + j * 4) = o;
    }
  }
  __syncthreads();
  float acc[4][4] = {};
  gemm_compute(As, Bs, acc);
  int tid = threadIdx.x, tx = tid & 15, ty = tid >> 4;
  int c0 = n0 + tx * 4;
  float4 b1v = *(const float4*)(b1 + c0);
#pragma unroll
  for (int i = 0; i < 4; ++i) {
    int m = m0 + ty * 4 + i;
    float4 r;
    r.x = fmaxf(acc[i][0] + b1v.x, 0.0f);
    r.y = fmaxf(acc[i][1] + b1v.y, 0.0f);
    r.z = fmaxf(acc[i][2] + b1v.z, 0.0f);
    r.w = fmaxf(acc[i][3] + b1v.w, 0.0f);
    *(float4*)&H1[(size_t)m * 1024 + c0] = r;
  }
}

__global__ __launch_bounds__(128) void ff2_kernel(
    const float* __restrict__ H1, const float* __restrict__ w2,
    const int* __restrict__ smask, float* __restrict__ outb)
{
  __shared__ __align__(16) float As[256][36];
  __shared__ __align__(16) float Bs[256][64];
  int m0 = blockIdx.y * 32, n0 = blockIdx.x * 64;
  int kbeg = blockIdx.z * 256;
  stage_B64(w2 + (size_t)kbeg * DMODEL, DMODEL, n0, Bs);
  stage_A_copy(H1, 1024, m0, kbeg, As);
  __syncthreads();
  float acc[4][4] = {};
  gemm_compute(As, Bs, acc);
  int tid = threadIdx.x, tx = tid & 15, ty = tid >> 4;
  int c0 = n0 + tx * 4;
#pragma unroll
  for (int i = 0; i < 4; ++i) {
    int m = m0 + ty * 4 + i;
    if (smask[m] == 0) {
      atomicAdd(&outb[(size_t)m * DMODEL + c0 + 0], acc[i][0]);
      atomicAdd(&outb[(size_t)m * DMODEL + c0 + 1], acc[i][1]);
      atomicAdd(&outb[(size_t)m * DMODEL + c0 + 2], acc[i][2]);
      atomicAdd(&outb[(size_t)m * DMODEL + c0 + 3], acc[i][3]);
    }
  }
}

__global__ __launch_bounds__(256) void attn_kernel(
    const float* __restrict__ Qb, const float* __restrict__ Kb, const float* __restrict__ Vb,
    const float* __restrict__ rpe, const int* __restrict__ tmask,
    const float* __restrict__ wrl, const float* __restrict__ brl,
    float* __restrict__ AO)
{
  __shared__ float Ks[256][32];
  __shared__ float Vt[32][260];
  __shared__ float ps[4][256];
  __shared__ float qs[16][32];
  __shared__ float wks[5][32];
  __shared__ float wvs[5][32];
  int bid = blockIdx.x;
  int b = bid >> 7, h = (bid >> 4) & 7, s0 = (bid & 15) << 4;
  int tid = threadIdx.x;
  const float* Kp = Kb + (size_t)(b * NH + h) * 8192;
  const float* Vp = Vb + (size_t)(b * NH + h) * 8192;
  {
    int t = tid;
    const float4* kr = (const float4*)(Kp + t * DH);
    const float4* vr = (const float4*)(Vp + t * DH);
    int sw = t & 7;
#pragma unroll
    for (int c = 0; c < 8; ++c) {
      float4 k4 = kr[c];
      *(float4*)&Ks[t][(c ^ sw) * 4] = k4;
    }
#pragma unroll
    for (int c = 0; c < 8; ++c) {
      float4 v4 = vr[c];
      Vt[c*4+0][t] = v4.x; Vt[c*4+1][t] = v4.y; Vt[c*4+2][t] = v4.z; Vt[c*4+3][t] = v4.w;
    }
  }
  if (tid < 160) {
    int j = tid >> 5, d = tid & 31;
    wks[j][d] = (j < 4) ? wrl[j * 512 + h * DH + d]       : brl[h * DH + d];
    wvs[j][d] = (j < 4) ? wrl[j * 512 + 256 + h * DH + d] : brl[256 + h * DH + d];
  }
  if (tid >= 128) {
    int u = tid - 128;
    int rr = u >> 3, cc = u & 7;
    *(float4*)&qs[rr][cc*4] =
        *(const float4*)&Qb[(b * 256 + s0 + rr) * DMODEL + h * DH + cc * 4];
  }
  __syncthreads();

  int w = tid >> 6, lane = tid & 63;
  int msk[4];
#pragma unroll
  for (int it = 0; it < 4; ++it) msk[it] = tmask[b * 256 + it * 64 + lane];

  for (int i = 0; i < 4; ++i) {
    int sl = w * 4 + i;
    int s = s0 + sl;
    float4 q4[8];
#pragma unroll
    for (int c = 0; c < 8; ++c) q4[c] = *(const float4*)&qs[sl][c * 4];
    float qw[4]; float qbr = 0.0f;
#pragma unroll
    for (int j = 0; j < 4; ++j) {
      float t0 = 0;
#pragma unroll
      for (int c = 0; c < 8; ++c) {
        float4 wv4 = *(const float4*)&wks[j][c * 4];
        t0 += q4[c].x*wv4.x + q4[c].y*wv4.y + q4[c].z*wv4.z + q4[c].w*wv4.w;
      }
      qw[j] = t0;
    }
#pragma unroll
    for (int c = 0; c < 8; ++c) {
      float4 wv4 = *(const float4*)&wks[4][c * 4];
      qbr += q4[c].x*wv4.x + q4[c].y*wv4.y + q4[c].z*wv4.z + q4[c].w*wv4.w;
    }
    const float4* rp4 = (const float4*)(rpe + (size_t)(b * 256 + s) * 1024);
    float sc[4]; float4 rr[4];
#pragma unroll
    for (int it = 0; it < 4; ++it) {
      int t = it * 64 + lane;
      int sw = t & 7;
      float sv = 0;
#pragma unroll
      for (int c = 0; c < 8; ++c) {
        float4 k4 = *(const float4*)&Ks[t][(c ^ sw) * 4];
        sv = fmaf(q4[c].x, k4.x, sv); sv = fmaf(q4[c].y, k4.y, sv);
        sv = fmaf(q4[c].z, k4.z, sv); sv = fmaf(q4[c].w, k4.w, sv);
      }
      float4 rv = rp4[t];
      rr[it] = rv;
      sv += rv.x*qw[0] + rv.y*qw[1] + rv.z*qw[2] + rv.w*qw[3] + qbr;
      if (msk[it] != 0) sv = NEG_INF;
      sc[it] = sv;
    }
    float mval = fmaxf(fmaxf(sc[0], sc[1]), fmaxf(sc[2], sc[3]));
#pragma unroll
    for (int off = 32; off >= 1; off >>= 1) mval = fmaxf(mval, __shfl_xor(mval, off));
    float p[4], lsum = 0;
#pragma unroll
    for (int it = 0; it < 4; ++it) { p[it] = __expf(sc[it] - mval); lsum += p[it]; }
    float wj0 = 0, wj1 = 0, wj2 = 0, wj3 = 0;
#pragma unroll
    for (int it = 0; it < 4; ++it) {
      wj0 = fmaf(p[it], rr[it].x, wj0);
      wj1 = fmaf(p[it], rr[it].y, wj1);
      wj2 = fmaf(p[it], rr[it].z, wj2);
      wj3 = fmaf(p[it], rr[it].w, wj3);
    }
#pragma unroll
    for (int off = 32; off >= 1; off >>= 1) {
      lsum += __shfl_xor(lsum, off);
      wj0 += __shfl_xor(wj0, off);
      wj1 += __shfl_xor(wj1, off);
      wj2 += __shfl_xor(wj2, off);
      wj3 += __shfl_xor(wj3, off);
    }
#pragma unroll
    for (int it = 0; it < 4; ++it) ps[w][it * 64 + lane] = p[it];
    int g = lane >> 5, d = lane & 31;
    float o = 0;
#pragma unroll
    for (int n = 0; n < 32; ++n) {
      int t = g * 128 + n * 4;
      float4 p4 = *(const float4*)&ps[w][t];
      float4 v4 = *(const float4*)&Vt[d][t];
      o += p4.x*v4.x + p4.y*v4.y + p4.z*v4.z + p4.w*v4.w;
    }
    o += __shfl_xor(o, 32);
    float corr = wj0 * wvs[0][d] + wj1 * wvs[1][d] + wj2 * wvs[2][d] + wj3 * wvs[3][d];
    float oval = (o + corr) / lsum + wvs[4][d];
    if (lane < 32) AO[(b * 256 + s) * DMODEL + h * DH + d] = oval;
  }
}

extern "C" void kernel_launch(void* const* d_in, const int* in_sizes, int n_in,
                              void* d_out, int out_size, void* d_ws, size_t ws_size,
                              hipStream_t stream)
{
  const float* src  = (const float*)d_in[0];
  const float* tgt  = (const float*)d_in[1];
  const float* rpe  = (const float*)d_in[2];
  const int*   smask = (const int*)d_in[3];
  const int*   tmask = (const int*)d_in[4];
  const float* ln1g = (const float*)d_in[5];
  const float* ln1b = (const float*)d_in[6];
  const float* lntg = (const float*)d_in[7];
  const float* lntb = (const float*)d_in[8];
  const float* ln2g = (const float*)d_in[9];
  const float* ln2b = (const float*)d_in[10];
  const float* wq = (const float*)d_in[11];
  const float* bq = (const float*)d_in[12];
  const float* wk = (const float*)d_in[13];
  const float* bk = (const float*)d_in[14];
  const float* wv = (const float*)d_in[15];
  const float* bv = (const float*)d_in[16];
  const float* wo = (const float*)d_in[17];
  const float* bo = (const float*)d_in[18];
  const float* wr = (const float*)d_in[19];
  const float* br = (const float*)d_in[20];
  const float* w1 = (const float*)d_in[21];
  const float* b1 = (const float*)d_in[22];
  const float* w2 = (const float*)d_in[23];
  const float* b2 = (const float*)d_in[24];

  float* w    = (float*)d_ws;
  float* Qb   = w;
  float* Kb   = w + 131072;
  float* Vb   = w + 262144;
  float* AO   = w + 393216;
  float* X    = w + 524288;
  float* SRC1 = w + 655360;
  float* H1   = w + 786432;

  MegaParams mp;
  mp.src = src; mp.tgt = tgt; mp.rpe = rpe; mp.smask = smask; mp.tmask = tmask;
  mp.ln1g = ln1g; mp.ln1b = ln1b; mp.lntg = lntg; mp.lntb = lntb;
  mp.ln2g = ln2g; mp.ln2b = ln2b;
  mp.wq = wq; mp.bq = bq; mp.wk = wk; mp.bk = bk; mp.wv = wv; mp.bv = bv;
  mp.wo = wo; mp.bo = bo; mp.wr = wr; mp.br = br;
  mp.w1 = w1; mp.b1 = b1; mp.w2 = w2; mp.b2 = b2;
  mp.out = (float*)d_out;
  mp.Qb = Qb; mp.Kb = Kb; mp.Vb = Vb; mp.AO = AO; mp.X = X; mp.SRC1 = SRC1; mp.H1 = H1;

  void* args[] = { &mp };
  hipError_t err = hipLaunchCooperativeKernel((const void*)mega_kernel,
                                              dim3(256), dim3(256), args, 0, stream);
  if (err != hipSuccess) {
    (void)hipGetLastError();   // clear; use verified split-kernel path
    for (int l = 0; l < 2; ++l) {
      const float* srcin = l ? SRC1 : src;
      float* outb = l ? (float*)d_out : SRC1;
      qkv_kernel<<<dim3(4, 16, 3), 128, 0, stream>>>(
          srcin, tgt, ln1g + l*256, ln1b + l*256, lntg + l*256, lntb + l*256,
          wq + l*65536, wk + l*65536, wv + l*65536,
          bq + l*256, bk + l*256, bv + l*256, Qb, Kb, Vb);
      attn_kernel<<<256, 256, 0, stream>>>(Qb, Kb, Vb, rpe, tmask,
                                           wr + l*2048, br + l*512, AO);
      wo_kernel<<<dim3(4, 16), 128, 0, stream>>>(AO, wo + l*65536, srcin, bo + l*256, X);
      ff1_kernel<<<dim3(16, 16), 128, 0, stream>>>(X, ln2g + l*256, ln2b + l*256,
                                                   w1 + l*262144, b1 + l*1024,
                                                   b2 + l*256, smask, H1, outb);
      ff2_kernel<<<dim3(4, 16, 4), 128, 0, stream>>>(H1, w2 + l*262144, smask, outb);
    }
  }
}

// Round 4
// 606.318 us; speedup vs baseline: 1.0101x; 1.0101x over previous
//
#include <hip/hip_runtime.h>
#include <math.h>

#define DMODEL 256
#define NH 8
#define DH 32
#define NEG_INF -1e30f

// ======================================================================
// Lightweight grid barrier: monotonic counter, agent-scope atomics,
// short-sleep spin. Counter zeroed via hipMemsetAsync before launch.
// ======================================================================
__device__ __forceinline__ void gbar(unsigned* cnt, unsigned target)
{
  __syncthreads();
  if (threadIdx.x == 0) {
    __threadfence();   // release all prior writes (device scope)
    __hip_atomic_fetch_add(cnt, 1u, __ATOMIC_ACQ_REL, __HIP_MEMORY_SCOPE_AGENT);
    while (__hip_atomic_load(cnt, __ATOMIC_ACQUIRE, __HIP_MEMORY_SCOPE_AGENT) < target) {
      __builtin_amdgcn_s_sleep(1);
    }
  }
  __syncthreads();
}

// ======================================================================
// Shared GEMM compute: 128 threads, 32x64 tile, micro 4x4, K=256
// ======================================================================
__device__ __forceinline__ void gemm_compute(const float (*__restrict__ As)[36],
                                             const float (*__restrict__ Bs)[64],
                                             float acc[4][4])
{
  int tid = threadIdx.x;
  int tx = tid & 15, ty = tid >> 4;     // tx: col/4 (0..15), ty: row/4 (0..7)
#pragma unroll 8
  for (int k = 0; k < 256; ++k) {
    float4 a  = *(const float4*)&As[k][ty * 4];
    float4 bv = *(const float4*)&Bs[k][tx * 4];
    acc[0][0] = fmaf(a.x, bv.x, acc[0][0]); acc[0][1] = fmaf(a.x, bv.y, acc[0][1]);
    acc[0][2] = fmaf(a.x, bv.z, acc[0][2]); acc[0][3] = fmaf(a.x, bv.w, acc[0][3]);
    acc[1][0] = fmaf(a.y, bv.x, acc[1][0]); acc[1][1] = fmaf(a.y, bv.y, acc[1][1]);
    acc[1][2] = fmaf(a.y, bv.z, acc[1][2]); acc[1][3] = fmaf(a.y, bv.w, acc[1][3]);
    acc[2][0] = fmaf(a.z, bv.x, acc[2][0]); acc[2][1] = fmaf(a.z, bv.y, acc[2][1]);
    acc[2][2] = fmaf(a.z, bv.z, acc[2][2]); acc[2][3] = fmaf(a.z, bv.w, acc[2][3]);
    acc[3][0] = fmaf(a.w, bv.x, acc[3][0]); acc[3][1] = fmaf(a.w, bv.y, acc[3][1]);
    acc[3][2] = fmaf(a.w, bv.z, acc[3][2]); acc[3][3] = fmaf(a.w, bv.w, acc[3][3]);
  }
}

// ---------------- 256-thread staging (megakernel) ----------------
__device__ __forceinline__ void stageB_256(const float* __restrict__ Bw, int ldb, int n0,
                                           float (*__restrict__ Bs)[64])
{
  int tid = threadIdx.x;
#pragma unroll
  for (int i = 0; i < 16; ++i) {
    int idx = tid + 256 * i;            // 0..4095 float4s
    int k = idx >> 4, c = (idx & 15) << 2;
    *(float4*)&Bs[k][c] = *(const float4*)(Bw + (size_t)k * ldb + n0 + c);
  }
}

__device__ __forceinline__ void stageA_copy_256(const float* __restrict__ A, int lda,
                                                int m0, int kbeg,
                                                float (*__restrict__ As)[36])
{
  int tid = threadIdx.x;
  int r = tid >> 3, p = tid & 7;        // row 0..31, eighth 0..7
  const float* row = A + (size_t)(m0 + r) * lda + kbeg + p * 32;
#pragma unroll
  for (int j = 0; j < 8; ++j) {
    float4 v = *(const float4*)(row + j * 4);
    int k = p * 32 + j * 4;
    As[k + 0][r] = v.x; As[k + 1][r] = v.y; As[k + 2][r] = v.z; As[k + 3][r] = v.w;
  }
}

__device__ __forceinline__ void stageA_ln_256(const float* __restrict__ Xsrc, int m0,
                                              const float* __restrict__ g,
                                              const float* __restrict__ b,
                                              float (*__restrict__ As)[36])
{
  int tid = threadIdx.x;
  int r = tid >> 3, p = tid & 7;
  const float* row = Xsrc + (size_t)(m0 + r) * DMODEL + p * 32;
  float4 v[8];
  float s = 0.f, ss = 0.f;
#pragma unroll
  for (int j = 0; j < 8; ++j) {
    v[j] = *(const float4*)(row + j * 4);
    s  += v[j].x + v[j].y + v[j].z + v[j].w;
    ss += v[j].x * v[j].x + v[j].y * v[j].y + v[j].z * v[j].z + v[j].w * v[j].w;
  }
  s  += __shfl_xor(s, 1);  s  += __shfl_xor(s, 2);  s  += __shfl_xor(s, 4);
  ss += __shfl_xor(ss, 1); ss += __shfl_xor(ss, 2); ss += __shfl_xor(ss, 4);
  float mean = s * (1.0f / 256.0f);
  float var  = ss * (1.0f / 256.0f) - mean * mean;
  float rstd = rsqrtf(var + 1e-5f);
#pragma unroll
  for (int j = 0; j < 8; ++j) {
    float4 gg = *(const float4*)(g + p * 32 + j * 4);
    float4 bb = *(const float4*)(b + p * 32 + j * 4);
    int k = p * 32 + j * 4;
    As[k + 0][r] = (v[j].x - mean) * rstd * gg.x + bb.x;
    As[k + 1][r] = (v[j].y - mean) * rstd * gg.y + bb.y;
    As[k + 2][r] = (v[j].z - mean) * rstd * gg.z + bb.z;
    As[k + 3][r] = (v[j].w - mean) * rstd * gg.w + bb.w;
  }
}

// ======================================================================
// Megakernel: 256 blocks x 256 threads, 9 custom grid barriers.
// Phase bodies identical to the verified split kernels.
// ======================================================================
struct MegaParams {
  const float* src; const float* tgt; const float* rpe;
  const int* smask; const int* tmask;
  const float* ln1g; const float* ln1b; const float* lntg; const float* lntb;
  const float* ln2g; const float* ln2b;
  const float* wq; const float* bq; const float* wk; const float* bk;
  const float* wv; const float* bv; const float* wo; const float* bo;
  const float* wr; const float* br; const float* w1; const float* b1;
  const float* w2; const float* b2;
  float* out; float* Qb; float* Kb; float* Vb; float* AO; float* X; float* SRC1; float* H1;
  unsigned* bar;
};

__global__ __launch_bounds__(256) void mega_kernel(MegaParams p)
{
  __shared__ __align__(16) float smem[25600];   // 102.4 KB union
  float (*As)[36]  = reinterpret_cast<float (*)[36]>(smem);          // 9216 floats
  float (*Bs)[64]  = reinterpret_cast<float (*)[64]>(smem + 9216);   // 16384 floats
  float (*Ks)[32]  = reinterpret_cast<float (*)[32]>(smem);          // 8192
  float (*Vt)[260] = reinterpret_cast<float (*)[260]>(smem + 8192);  // 8320
  float (*ps)[256] = reinterpret_cast<float (*)[256]>(smem + 16512); // 1024
  float (*qs)[32]  = reinterpret_cast<float (*)[32]>(smem + 17536);  // 512
  float (*wks)[32] = reinterpret_cast<float (*)[32]>(smem + 18048);  // 160
  float (*wvs)[32] = reinterpret_cast<float (*)[32]>(smem + 18208);  // 160
  int bid = blockIdx.x, tid = threadIdx.x;
  unsigned step = 0;

  for (int l = 0; l < 2; ++l) {
    const float* srcin = l ? p.SRC1 : p.src;
    float* outb = l ? p.out : p.SRC1;
    const float* wq = p.wq + l * 65536;  const float* bq = p.bq + l * 256;
    const float* wk = p.wk + l * 65536;  const float* bk = p.bk + l * 256;
    const float* wv = p.wv + l * 65536;  const float* bv = p.bv + l * 256;
    const float* wo = p.wo + l * 65536;  const float* bo = p.bo + l * 256;
    const float* wr = p.wr + l * 2048;   const float* br = p.br + l * 512;
    const float* w1 = p.w1 + l * 262144; const float* b1 = p.b1 + l * 1024;
    const float* w2 = p.w2 + l * 262144; const float* b2 = p.b2 + l * 256;
    const float* ln1g = p.ln1g + l * 256; const float* ln1b = p.ln1b + l * 256;
    const float* lntg = p.lntg + l * 256; const float* lntb = p.lntb + l * 256;
    const float* ln2g = p.ln2g + l * 256; const float* ln2b = p.ln2b + l * 256;

    // ===== phase 1: QKV (192 tasks) =====
    if (bid < 192) {
      int x = bid & 3, y = (bid >> 2) & 15, z = bid >> 6;
      int m0 = y * 32, n0 = x * 64;
      const float* Bw = (z == 0) ? wq : (z == 1) ? wk : wv;
      stageB_256(Bw, DMODEL, n0, Bs);
      if (z == 0) stageA_ln_256(srcin, m0, ln1g, ln1b, As);
      else        stageA_ln_256(p.tgt, m0, lntg, lntb, As);
      __syncthreads();
      if (tid < 128) {
        float acc[4][4] = {};
        gemm_compute(As, Bs, acc);
        const float* bias = (z == 0) ? bq : (z == 1) ? bk : bv;
        int tx = tid & 15, ty = tid >> 4;
        int c0 = n0 + tx * 4;
        float4 bias4 = *(const float4*)(bias + c0);
        const float scale = 0.1767766952966369f;  // 1/sqrt(32)
#pragma unroll
        for (int i = 0; i < 4; ++i) {
          int m = m0 + ty * 4 + i;
          float4 r;
          r.x = acc[i][0] + bias4.x;
          r.y = acc[i][1] + bias4.y;
          r.z = acc[i][2] + bias4.z;
          r.w = acc[i][3] + bias4.w;
          if (z == 0) {
            r.x *= scale; r.y *= scale; r.z *= scale; r.w *= scale;
            *(float4*)&p.Qb[m * DMODEL + c0] = r;
          } else {
            int b_ = m >> 8, t = m & 255, h = c0 >> 5, d0 = c0 & 31;
            float* dst = ((z == 1) ? p.Kb : p.Vb) + (size_t)(b_ * NH + h) * 8192 + t * DH + d0;
            *(float4*)dst = r;
          }
        }
      }
    }
    gbar(p.bar, ++step * 256u);

    // ===== phase 2: attention (256 tasks) =====
    {
      int ab = bid >> 7, h = (bid >> 4) & 7, s0 = (bid & 15) << 4;
      const float* Kp = p.Kb + (size_t)(ab * NH + h) * 8192;
      const float* Vp = p.Vb + (size_t)(ab * NH + h) * 8192;
      {
        int t = tid;
        const float4* kr = (const float4*)(Kp + t * DH);
        const float4* vr = (const float4*)(Vp + t * DH);
        int sw = t & 7;
#pragma unroll
        for (int c = 0; c < 8; ++c) {
          float4 k4 = kr[c];
          *(float4*)&Ks[t][(c ^ sw) * 4] = k4;
        }
#pragma unroll
        for (int c = 0; c < 8; ++c) {
          float4 v4 = vr[c];
          Vt[c*4+0][t] = v4.x; Vt[c*4+1][t] = v4.y; Vt[c*4+2][t] = v4.z; Vt[c*4+3][t] = v4.w;
        }
      }
      if (tid < 160) {
        int j = tid >> 5, d = tid & 31;
        wks[j][d] = (j < 4) ? wr[j * 512 + h * DH + d]       : br[h * DH + d];
        wvs[j][d] = (j < 4) ? wr[j * 512 + 256 + h * DH + d] : br[256 + h * DH + d];
      }
      if (tid >= 128) {
        int u = tid - 128;
        int rr_ = u >> 3, cc = u & 7;
        *(float4*)&qs[rr_][cc*4] =
            *(const float4*)&p.Qb[(ab * 256 + s0 + rr_) * DMODEL + h * DH + cc * 4];
      }
      __syncthreads();

      int w = tid >> 6, lane = tid & 63;
      int msk[4];
#pragma unroll
      for (int it = 0; it < 4; ++it) msk[it] = p.tmask[ab * 256 + it * 64 + lane];

      for (int i = 0; i < 4; ++i) {
        int sl = w * 4 + i;
        int s = s0 + sl;
        float4 q4[8];
#pragma unroll
        for (int c = 0; c < 8; ++c) q4[c] = *(const float4*)&qs[sl][c * 4];
        float qw[4]; float qbr = 0.0f;
#pragma unroll
        for (int j = 0; j < 4; ++j) {
          float t0 = 0;
#pragma unroll
          for (int c = 0; c < 8; ++c) {
            float4 wv4 = *(const float4*)&wks[j][c * 4];
            t0 += q4[c].x*wv4.x + q4[c].y*wv4.y + q4[c].z*wv4.z + q4[c].w*wv4.w;
          }
          qw[j] = t0;
        }
#pragma unroll
        for (int c = 0; c < 8; ++c) {
          float4 wv4 = *(const float4*)&wks[4][c * 4];
          qbr += q4[c].x*wv4.x + q4[c].y*wv4.y + q4[c].z*wv4.z + q4[c].w*wv4.w;
        }
        const float4* rp4 = (const float4*)(p.rpe + (size_t)(ab * 256 + s) * 1024);
        float sc[4]; float4 rr[4];
#pragma unroll
        for (int it = 0; it < 4; ++it) {
          int t = it * 64 + lane;
          int sw = t & 7;
          float sv = 0;
#pragma unroll
          for (int c = 0; c < 8; ++c) {
            float4 k4 = *(const float4*)&Ks[t][(c ^ sw) * 4];
            sv = fmaf(q4[c].x, k4.x, sv); sv = fmaf(q4[c].y, k4.y, sv);
            sv = fmaf(q4[c].z, k4.z, sv); sv = fmaf(q4[c].w, k4.w, sv);
          }
          float4 rv = rp4[t];
          rr[it] = rv;
          sv += rv.x*qw[0] + rv.y*qw[1] + rv.z*qw[2] + rv.w*qw[3] + qbr;
          if (msk[it] != 0) sv = NEG_INF;
          sc[it] = sv;
        }
        float mval = fmaxf(fmaxf(sc[0], sc[1]), fmaxf(sc[2], sc[3]));
#pragma unroll
        for (int off = 32; off >= 1; off >>= 1) mval = fmaxf(mval, __shfl_xor(mval, off));
        float pr[4], lsum = 0;
#pragma unroll
        for (int it = 0; it < 4; ++it) { pr[it] = __expf(sc[it] - mval); lsum += pr[it]; }
        float wj0 = 0, wj1 = 0, wj2 = 0, wj3 = 0;
#pragma unroll
        for (int it = 0; it < 4; ++it) {
          wj0 = fmaf(pr[it], rr[it].x, wj0);
          wj1 = fmaf(pr[it], rr[it].y, wj1);
          wj2 = fmaf(pr[it], rr[it].z, wj2);
          wj3 = fmaf(pr[it], rr[it].w, wj3);
        }
#pragma unroll
        for (int off = 32; off >= 1; off >>= 1) {
          lsum += __shfl_xor(lsum, off);
          wj0 += __shfl_xor(wj0, off);
          wj1 += __shfl_xor(wj1, off);
          wj2 += __shfl_xor(wj2, off);
          wj3 += __shfl_xor(wj3, off);
        }
#pragma unroll
        for (int it = 0; it < 4; ++it) ps[w][it * 64 + lane] = pr[it];
        int g = lane >> 5, d = lane & 31;
        float o = 0;
#pragma unroll
        for (int n = 0; n < 32; ++n) {
          int t = g * 128 + n * 4;
          float4 p4 = *(const float4*)&ps[w][t];
          float4 v4 = *(const float4*)&Vt[d][t];
          o += p4.x*v4.x + p4.y*v4.y + p4.z*v4.z + p4.w*v4.w;
        }
        o += __shfl_xor(o, 32);
        float corr = wj0 * wvs[0][d] + wj1 * wvs[1][d] + wj2 * wvs[2][d] + wj3 * wvs[3][d];
        float oval = (o + corr) / lsum + wvs[4][d];
        if (lane < 32) p.AO[(ab * 256 + s) * DMODEL + h * DH + d] = oval;
      }
    }
    gbar(p.bar, ++step * 256u);

    // ===== phase 3: wo + residual (64 tasks) =====
    if (bid < 64) {
      int x = bid & 3, y = bid >> 2;
      int m0 = y * 32, n0 = x * 64;
      stageB_256(wo, DMODEL, n0, Bs);
      stageA_copy_256(p.AO, DMODEL, m0, 0, As);
      __syncthreads();
      if (tid < 128) {
        float acc[4][4] = {};
        gemm_compute(As, Bs, acc);
        int tx = tid & 15, ty = tid >> 4;
        int c0 = n0 + tx * 4;
        float4 bov = *(const float4*)(bo + c0);
#pragma unroll
        for (int i = 0; i < 4; ++i) {
          int m = m0 + ty * 4 + i;
          float4 sv = *(const float4*)(srcin + (size_t)m * DMODEL + c0);
          float4 r;
          r.x = sv.x + bov.x + acc[i][0];
          r.y = sv.y + bov.y + acc[i][1];
          r.z = sv.z + bov.z + acc[i][2];
          r.w = sv.w + bov.w + acc[i][3];
          *(float4*)&p.X[(size_t)m * DMODEL + c0] = r;
        }
      }
    }
    gbar(p.bar, ++step * 256u);

    // ===== phase 4: FF1 + LN2 + ReLU; x==0 writes out-init (256 tasks) =====
    {
      int x = bid & 15, y = bid >> 4;
      int m0 = y * 32, n0 = x * 64;
      stageB_256(w1, 1024, n0, Bs);
      stageA_ln_256(p.X, m0, ln2g, ln2b, As);
      if (x == 0 && tid < 128) {
        int r = tid >> 2, pq = tid & 3;
        int m = m0 + r;
        float mm = (p.smask[m] != 0) ? 0.0f : 1.0f;
#pragma unroll
        for (int j = 0; j < 16; ++j) {
          float4 xv  = *(const float4*)(p.X + (size_t)m * DMODEL + pq * 64 + j * 4);
          float4 b2v = *(const float4*)(b2 + pq * 64 + j * 4);
          float4 o;
          o.x = mm * (xv.x + b2v.x); o.y = mm * (xv.y + b2v.y);
          o.z = mm * (xv.z + b2v.z); o.w = mm * (xv.w + b2v.w);
          *(float4*)(outb + (size_t)m * DMODEL + pq * 64 + j * 4) = o;
        }
      }
      __syncthreads();
      if (tid < 128) {
        float acc[4][4] = {};
        gemm_compute(As, Bs, acc);
        int tx = tid & 15, ty = tid >> 4;
        int c0 = n0 + tx * 4;
        float4 b1v = *(const float4*)(b1 + c0);
#pragma unroll
        for (int i = 0; i < 4; ++i) {
          int m = m0 + ty * 4 + i;
          float4 r;
          r.x = fmaxf(acc[i][0] + b1v.x, 0.0f);
          r.y = fmaxf(acc[i][1] + b1v.y, 0.0f);
          r.z = fmaxf(acc[i][2] + b1v.z, 0.0f);
          r.w = fmaxf(acc[i][3] + b1v.w, 0.0f);
          *(float4*)&p.H1[(size_t)m * 1024 + c0] = r;
        }
      }
    }
    gbar(p.bar, ++step * 256u);

    // ===== phase 5: FF2 split-K=4, masked atomic accumulate (256 tasks) =====
    {
      int x = bid & 3, y = (bid >> 2) & 15, z = bid >> 6;
      int m0 = y * 32, n0 = x * 64;
      int kbeg = z * 256;
      stageB_256(w2 + (size_t)kbeg * DMODEL, DMODEL, n0, Bs);
      stageA_copy_256(p.H1, 1024, m0, kbeg, As);
      __syncthreads();
      if (tid < 128) {
        float acc[4][4] = {};
        gemm_compute(As, Bs, acc);
        int tx = tid & 15, ty = tid >> 4;
        int c0 = n0 + tx * 4;
#pragma unroll
        for (int i = 0; i < 4; ++i) {
          int m = m0 + ty * 4 + i;
          if (p.smask[m] == 0) {
            atomicAdd(&outb[(size_t)m * DMODEL + c0 + 0], acc[i][0]);
            atomicAdd(&outb[(size_t)m * DMODEL + c0 + 1], acc[i][1]);
            atomicAdd(&outb[(size_t)m * DMODEL + c0 + 2], acc[i][2]);
            atomicAdd(&outb[(size_t)m * DMODEL + c0 + 3], acc[i][3]);
          }
        }
      }
    }
    if (l == 0) gbar(p.bar, ++step * 256u);
  }
}

// ======================================================================
// Fallback: verified round-2 split kernels (used if cooperative launch fails)
// ======================================================================
__device__ __forceinline__ void stage_B64(const float* __restrict__ Bw, int ldb, int n0,
                                          float (*__restrict__ Bs)[64])
{
  int tid = threadIdx.x;
#pragma unroll
  for (int i = 0; i < 32; ++i) {
    int idx = tid + 128 * i;
    int k = idx >> 4, c = (idx & 15) << 2;
    *(float4*)&Bs[k][c] = *(const float4*)(Bw + (size_t)k * ldb + n0 + c);
  }
}

__device__ __forceinline__ void stage_A_copy(const float* __restrict__ A, int lda,
                                             int m0, int kbeg,
                                             float (*__restrict__ As)[36])
{
  int tid = threadIdx.x;
  int r = tid >> 2, p = tid & 3;
  const float* row = A + (size_t)(m0 + r) * lda + kbeg + p * 64;
#pragma unroll
  for (int j = 0; j < 16; ++j) {
    float4 v = *(const float4*)(row + j * 4);
    int k = p * 64 + j * 4;
    As[k + 0][r] = v.x; As[k + 1][r] = v.y; As[k + 2][r] = v.z; As[k + 3][r] = v.w;
  }
}

__device__ __forceinline__ void stage_A_ln(const float* __restrict__ Xsrc, int m0,
                                           const float* __restrict__ g,
                                           const float* __restrict__ b,
                                           float (*__restrict__ As)[36])
{
  int tid = threadIdx.x;
  int r = tid >> 2, p = tid & 3;
  const float* row = Xsrc + (size_t)(m0 + r) * DMODEL + p * 64;
  float4 v[16];
  float s = 0.f, ss = 0.f;
#pragma unroll
  for (int j = 0; j < 16; ++j) {
    v[j] = *(const float4*)(row + j * 4);
    s  += v[j].x + v[j].y + v[j].z + v[j].w;
    ss += v[j].x * v[j].x + v[j].y * v[j].y + v[j].z * v[j].z + v[j].w * v[j].w;
  }
  s  += __shfl_xor(s, 1);  s  += __shfl_xor(s, 2);
  ss += __shfl_xor(ss, 1); ss += __shfl_xor(ss, 2);
  float mean = s * (1.0f / 256.0f);
  float var  = ss * (1.0f / 256.0f) - mean * mean;
  float rstd = rsqrtf(var + 1e-5f);
#pragma unroll
  for (int j = 0; j < 16; ++j) {
    float4 gg = *(const float4*)(g + p * 64 + j * 4);
    float4 bb = *(const float4*)(b + p * 64 + j * 4);
    int k = p * 64 + j * 4;
    As[k + 0][r] = (v[j].x - mean) * rstd * gg.x + bb.x;
    As[k + 1][r] = (v[j].y - mean) * rstd * gg.y + bb.y;
    As[k + 2][r] = (v[j].z - mean) * rstd * gg.z + bb.z;
    As[k + 3][r] = (v[j].w - mean) * rstd * gg.w + bb.w;
  }
}

__global__ __launch_bounds__(128) void qkv_kernel(
    const float* __restrict__ srcin, const float* __restrict__ tgt,
    const float* __restrict__ ln1g, const float* __restrict__ ln1b,
    const float* __restrict__ lntg, const float* __restrict__ lntb,
    const float* __restrict__ wq, const float* __restrict__ wk, const float* __restrict__ wv,
    const float* __restrict__ bq, const float* __restrict__ bk, const float* __restrict__ bv,
    float* __restrict__ Qb, float* __restrict__ Kb, float* __restrict__ Vb)
{
  __shared__ __align__(16) float As[256][36];
  __shared__ __align__(16) float Bs[256][64];
  int z = blockIdx.z;
  int m0 = blockIdx.y * 32, n0 = blockIdx.x * 64;
  const float* Bw = (z == 0) ? wq : (z == 1) ? wk : wv;
  stage_B64(Bw, DMODEL, n0, Bs);
  if (z == 0) stage_A_ln(srcin, m0, ln1g, ln1b, As);
  else        stage_A_ln(tgt,   m0, lntg, lntb, As);
  __syncthreads();
  float acc[4][4] = {};
  gemm_compute(As, Bs, acc);
  const float* bias = (z == 0) ? bq : (z == 1) ? bk : bv;
  int tid = threadIdx.x, tx = tid & 15, ty = tid >> 4;
  int c0 = n0 + tx * 4;
  float4 bias4 = *(const float4*)(bias + c0);
  const float scale = 0.1767766952966369f;
#pragma unroll
  for (int i = 0; i < 4; ++i) {
    int m = m0 + ty * 4 + i;
    float4 r;
    r.x = acc[i][0] + bias4.x;
    r.y = acc[i][1] + bias4.y;
    r.z = acc[i][2] + bias4.z;
    r.w = acc[i][3] + bias4.w;
    if (z == 0) {
      r.x *= scale; r.y *= scale; r.z *= scale; r.w *= scale;
      *(float4*)&Qb[m * DMODEL + c0] = r;
    } else {
      int b = m >> 8, t = m & 255, h = c0 >> 5, d0 = c0 & 31;
      float* dst = ((z == 1) ? Kb : Vb) + (size_t)(b * NH + h) * 8192 + t * DH + d0;
      *(float4*)dst = r;
    }
  }
}

__global__ __launch_bounds__(128) void wo_kernel(
    const float* __restrict__ AO, const float* __restrict__ wo,
    const float* __restrict__ srcin, const float* __restrict__ bo,
    float* __restrict__ X)
{
  __shared__ __align__(16) float As[256][36];
  __shared__ __align__(16) float Bs[256][64];
  int m0 = blockIdx.y * 32, n0 = blockIdx.x * 64;
  stage_B64(wo, DMODEL, n0, Bs);
  stage_A_copy(AO, DMODEL, m0, 0, As);
  __syncthreads();
  float acc[4][4] = {};
  gemm_compute(As, Bs, acc);
  int tid = threadIdx.x, tx = tid & 15, ty = tid >> 4;
  int c0 = n0 + tx * 4;
  float4 bov = *(const float4*)(bo + c0);
#pragma unroll
  for (int i = 0; i < 4; ++i) {
    int m = m0 + ty * 4 + i;
    float4 sv = *(const float4*)(srcin + (size_t)m * DMODEL + c0);
    float4 r;
    r.x = sv.x + bov.x + acc[i][0];
    r.y = sv.y + bov.y + acc[i][1];
    r.z = sv.z + bov.z + acc[i][2];
    r.w = sv.w + bov.w + acc[i][3];
    *(float4*)&X[(size_t)m * DMODEL + c0] = r;
  }
}

__global__ __launch_bounds__(128) void ff1_kernel(
    const float* __restrict__ X, const float* __restrict__ ln2g, const float* __restrict__ ln2b,
    const float* __restrict__ w1, const float* __restrict__ b1,
    const float* __restrict__ b2, const int* __restrict__ smask,
    float* __restrict__ H1, float* __restrict__ outb)
{
  __shared__ __align__(16) float As[256][36];
  __shared__ __align__(16) float Bs[256][64];
  int m0 = blockIdx.y * 32, n0 = blockIdx.x * 64;
  stage_B64(w1, 1024, n0, Bs);
  stage_A_ln(X, m0, ln2g, ln2b, As);
  if (blockIdx.x == 0) {
    int tid = threadIdx.x;
    int r = tid >> 2, p = tid & 3;
    int m = m0 + r;
    float mm = (smask[m] != 0) ? 0.0f : 1.0f;
#pragma unroll
    for (int j = 0; j < 16; ++j) {
      float4 xv  = *(const float4*)(X  + (size_t)m * DMODEL + p * 64 + j * 4);
      float4 b2v = *(const float4*)(b2 + p * 64 + j * 4);
      float4 o;
      o.x = mm * (xv.x + b2v.x); o.y = mm * (xv.y + b2v.y);
      o.z = mm * (xv.z + b2v.z); o.w = mm * (xv.w + b2v.w);
      *(float4*)(outb + (size_t)m * DMODEL + p * 64 + j * 4) = o;
    }
  }
  __syncthreads();
  float acc[4][4] = {};
  gemm_compute(As, Bs, acc);
  int tid = threadIdx.x, tx = tid & 15, ty = tid >> 4;
  int c0 = n0 + tx * 4;
  float4 b1v = *(const float4*)(b1 + c0);
#pragma unroll
  for (int i = 0; i < 4; ++i) {
    int m = m0 + ty * 4 + i;
    float4 r;
    r.x = fmaxf(acc[i][0] + b1v.x, 0.0f);
    r.y = fmaxf(acc[i][1] + b1v.y, 0.0f);
    r.z = fmaxf(acc[i][2] + b1v.z, 0.0f);
    r.w = fmaxf(acc[i][3] + b1v.w, 0.0f);
    *(float4*)&H1[(size_t)m * 1024 + c0] = r;
  }
}

__global__ __launch_bounds__(128) void ff2_kernel(
    const float* __restrict__ H1, const float* __restrict__ w2,
    const int* __restrict__ smask, float* __restrict__ outb)
{
  __shared__ __align__(16) float As[256][36];
  __shared__ __align__(16) float Bs[256][64];
  int m0 = blockIdx.y * 32, n0 = blockIdx.x * 64;
  int kbeg = blockIdx.z * 256;
  stage_B64(w2 + (size_t)kbeg * DMODEL, DMODEL, n0, Bs);
  stage_A_copy(H1, 1024, m0, kbeg, As);
  __syncthreads();
  float acc[4][4] = {};
  gemm_compute(As, Bs, acc);
  int tid = threadIdx.x, tx = tid & 15, ty = tid >> 4;
  int c0 = n0 + tx * 4;
#pragma unroll
  for (int i = 0; i < 4; ++i) {
    int m = m0 + ty * 4 + i;
    if (smask[m] == 0) {
      atomicAdd(&outb[(size_t)m * DMODEL + c0 + 0], acc[i][0]);
      atomicAdd(&outb[(size_t)m * DMODEL + c0 + 1], acc[i][1]);
      atomicAdd(&outb[(size_t)m * DMODEL + c0 + 2], acc[i][2]);
      atomicAdd(&outb[(size_t)m * DMODEL + c0 + 3], acc[i][3]);
    }
  }
}

__global__ __launch_bounds__(256) void attn_kernel(
    const float* __restrict__ Qb, const float* __restrict__ Kb, const float* __restrict__ Vb,
    const float* __restrict__ rpe, const int* __restrict__ tmask,
    const float* __restrict__ wrl, const float* __restrict__ brl,
    float* __restrict__ AO)
{
  __shared__ float Ks[256][32];
  __shared__ float Vt[32][260];
  __shared__ float ps[4][256];
  __shared__ float qs[16][32];
  __shared__ float wks[5][32];
  __shared__ float wvs[5][32];
  int bid = blockIdx.x;
  int b = bid >> 7, h = (bid >> 4) & 7, s0 = (bid & 15) << 4;
  int tid = threadIdx.x;
  const float* Kp = Kb + (size_t)(b * NH + h) * 8192;
  const float* Vp = Vb + (size_t)(b * NH + h) * 8192;
  {
    int t = tid;
    const float4* kr = (const float4*)(Kp + t * DH);
    const float4* vr = (const float4*)(Vp + t * DH);
    int sw = t & 7;
#pragma unroll
    for (int c = 0; c < 8; ++c) {
      float4 k4 = kr[c];
      *(float4*)&Ks[t][(c ^ sw) * 4] = k4;
    }
#pragma unroll
    for (int c = 0; c < 8; ++c) {
      float4 v4 = vr[c];
      Vt[c*4+0][t] = v4.x; Vt[c*4+1][t] = v4.y; Vt[c*4+2][t] = v4.z; Vt[c*4+3][t] = v4.w;
    }
  }
  if (tid < 160) {
    int j = tid >> 5, d = tid & 31;
    wks[j][d] = (j < 4) ? wrl[j * 512 + h * DH + d]       : brl[h * DH + d];
    wvs[j][d] = (j < 4) ? wrl[j * 512 + 256 + h * DH + d] : brl[256 + h * DH + d];
  }
  if (tid >= 128) {
    int u = tid - 128;
    int rr = u >> 3, cc = u & 7;
    *(float4*)&qs[rr][cc*4] =
        *(const float4*)&Qb[(b * 256 + s0 + rr) * DMODEL + h * DH + cc * 4];
  }
  __syncthreads();

  int w = tid >> 6, lane = tid & 63;
  int msk[4];
#pragma unroll
  for (int it = 0; it < 4; ++it) msk[it] = tmask[b * 256 + it * 64 + lane];

  for (int i = 0; i < 4; ++i) {
    int sl = w * 4 + i;
    int s = s0 + sl;
    float4 q4[8];
#pragma unroll
    for (int c = 0; c < 8; ++c) q4[c] = *(const float4*)&qs[sl][c * 4];
    float qw[4]; float qbr = 0.0f;
#pragma unroll
    for (int j = 0; j < 4; ++j) {
      float t0 = 0;
#pragma unroll
      for (int c = 0; c < 8; ++c) {
        float4 wv4 = *(const float4*)&wks[j][c * 4];
        t0 += q4[c].x*wv4.x + q4[c].y*wv4.y + q4[c].z*wv4.z + q4[c].w*wv4.w;
      }
      qw[j] = t0;
    }
#pragma unroll
    for (int c = 0; c < 8; ++c) {
      float4 wv4 = *(const float4*)&wks[4][c * 4];
      qbr += q4[c].x*wv4.x + q4[c].y*wv4.y + q4[c].z*wv4.z + q4[c].w*wv4.w;
    }
    const float4* rp4 = (const float4*)(rpe + (size_t)(b * 256 + s) * 1024);
    float sc[4]; float4 rr[4];
#pragma unroll
    for (int it = 0; it < 4; ++it) {
      int t = it * 64 + lane;
      int sw = t & 7;
      float sv = 0;
#pragma unroll
      for (int c = 0; c < 8; ++c) {
        float4 k4 = *(const float4*)&Ks[t][(c ^ sw) * 4];
        sv = fmaf(q4[c].x, k4.x, sv); sv = fmaf(q4[c].y, k4.y, sv);
        sv = fmaf(q4[c].z, k4.z, sv); sv = fmaf(q4[c].w, k4.w, sv);
      }
      float4 rv = rp4[t];
      rr[it] = rv;
      sv += rv.x*qw[0] + rv.y*qw[1] + rv.z*qw[2] + rv.w*qw[3] + qbr;
      if (msk[it] != 0) sv = NEG_INF;
      sc[it] = sv;
    }
    float mval = fmaxf(fmaxf(sc[0], sc[1]), fmaxf(sc[2], sc[3]));
#pragma unroll
    for (int off = 32; off >= 1; off >>= 1) mval = fmaxf(mval, __shfl_xor(mval, off));
    float p[4], lsum = 0;
#pragma unroll
    for (int it = 0; it < 4; ++it) { p[it] = __expf(sc[it] - mval); lsum += p[it]; }
    float wj0 = 0, wj1 = 0, wj2 = 0, wj3 = 0;
#pragma unroll
    for (int it = 0; it < 4; ++it) {
      wj0 = fmaf(p[it], rr[it].x, wj0);
      wj1 = fmaf(p[it], rr[it].y, wj1);
      wj2 = fmaf(p[it], rr[it].z, wj2);
      wj3 = fmaf(p[it], rr[it].w, wj3);
    }
#pragma unroll
    for (int off = 32; off >= 1; off >>= 1) {
      lsum += __shfl_xor(lsum, off);
      wj0 += __shfl_xor(wj0, off);
      wj1 += __shfl_xor(wj1, off);
      wj2 += __shfl_xor(wj2, off);
      wj3 += __shfl_xor(wj3, off);
    }
#pragma unroll
    for (int it = 0; it < 4; ++it) ps[w][it * 64 + lane] = p[it];
    int g = lane >> 5, d = lane & 31;
    float o = 0;
#pragma unroll
    for (int n = 0; n < 32; ++n) {
      int t = g * 128 + n * 4;
      float4 p4 = *(const float4*)&ps[w][t];
      float4 v4 = *(const float4*)&Vt[d][t];
      o += p4.x*v4.x + p4.y*v4.y + p4.z*v4.z + p4.w*v4.w;
    }
    o += __shfl_xor(o, 32);
    float corr = wj0 * wvs[0][d] + wj1 * wvs[1][d] + wj2 * wvs[2][d] + wj3 * wvs[3][d];
    float oval = (o + corr) / lsum + wvs[4][d];
    if (lane < 32) AO[(b * 256 + s) * DMODEL + h * DH + d] = oval;
  }
}

extern "C" void kernel_launch(void* const* d_in, const int* in_sizes, int n_in,
                              void* d_out, int out_size, void* d_ws, size_t ws_size,
                              hipStream_t stream)
{
  const float* src  = (const float*)d_in[0];
  const float* tgt  = (const float*)d_in[1];
  const float* rpe  = (const float*)d_in[2];
  const int*   smask = (const int*)d_in[3];
  const int*   tmask = (const int*)d_in[4];
  const float* ln1g = (const float*)d_in[5];
  const float* ln1b = (const float*)d_in[6];
  const float* lntg = (const float*)d_in[7];
  const float* lntb = (const float*)d_in[8];
  const float* ln2g = (const float*)d_in[9];
  const float* ln2b = (const float*)d_in[10];
  const float* wq = (const float*)d_in[11];
  const float* bq = (const float*)d_in[12];
  const float* wk = (const float*)d_in[13];
  const float* bk = (const float*)d_in[14];
  const float* wv = (const float*)d_in[15];
  const float* bv = (const float*)d_in[16];
  const float* wo = (const float*)d_in[17];
  const float* bo = (const float*)d_in[18];
  const float* wr = (const float*)d_in[19];
  const float* br = (const float*)d_in[20];
  const float* w1 = (const float*)d_in[21];
  const float* b1 = (const float*)d_in[22];
  const float* w2 = (const float*)d_in[23];
  const float* b2 = (const float*)d_in[24];

  float* w    = (float*)d_ws;
  float* Qb   = w;
  float* Kb   = w + 131072;
  float* Vb   = w + 262144;
  float* AO   = w + 393216;
  float* X    = w + 524288;
  float* SRC1 = w + 655360;
  float* H1   = w + 786432;             // 512*1024
  unsigned* bar = (unsigned*)(w + 1572864);  // 6 MB offset, clear of all buffers

  MegaParams mp;
  mp.src = src; mp.tgt = tgt; mp.rpe = rpe; mp.smask = smask; mp.tmask = tmask;
  mp.ln1g = ln1g; mp.ln1b = ln1b; mp.lntg = lntg; mp.lntb = lntb;
  mp.ln2g = ln2g; mp.ln2b = ln2b;
  mp.wq = wq; mp.bq = bq; mp.wk = wk; mp.bk = bk; mp.wv = wv; mp.bv = bv;
  mp.wo = wo; mp.bo = bo; mp.wr = wr; mp.br = br;
  mp.w1 = w1; mp.b1 = b1; mp.w2 = w2; mp.b2 = b2;
  mp.out = (float*)d_out;
  mp.Qb = Qb; mp.Kb = Kb; mp.Vb = Vb; mp.AO = AO; mp.X = X; mp.SRC1 = SRC1; mp.H1 = H1;
  mp.bar = bar;

  hipMemsetAsync(bar, 0, 64, stream);   // reset barrier counter each replay

  void* args[] = { &mp };
  hipError_t err = hipLaunchCooperativeKernel((const void*)mega_kernel,
                                              dim3(256), dim3(256), args, 0, stream);
  if (err != hipSuccess) {
    (void)hipGetLastError();   // clear; use verified split-kernel path
    for (int l = 0; l < 2; ++l) {
      const float* srcin = l ? SRC1 : src;
      float* outb = l ? (float*)d_out : SRC1;
      qkv_kernel<<<dim3(4, 16, 3), 128, 0, stream>>>(
          srcin, tgt, ln1g + l*256, ln1b + l*256, lntg + l*256, lntb + l*256,
          wq + l*65536, wk + l*65536, wv + l*65536,
          bq + l*256, bk + l*256, bv + l*256, Qb, Kb, Vb);
      attn_kernel<<<256, 256, 0, stream>>>(Qb, Kb, Vb, rpe, tmask,
                                           wr + l*2048, br + l*512, AO);
      wo_kernel<<<dim3(4, 16), 128, 0, stream>>>(AO, wo + l*65536, srcin, bo + l*256, X);
      ff1_kernel<<<dim3(16, 16), 128, 0, stream>>>(X, ln2g + l*256, ln2b + l*256,
                                                   w1 + l*262144, b1 + l*1024,
                                                   b2 + l*256, smask, H1, outb);
      ff2_kernel<<<dim3(4, 16, 4), 128, 0, stream>>>(H1, w2 + l*262144, smask, outb);
    }
  }
}

// Round 5
// 540.816 us; speedup vs baseline: 1.1324x; 1.1211x over previous
//
#include <hip/hip_runtime.h>
#include <math.h>

#define DMODEL 256
#define NH 8
#define DH 32
#define NEG_INF -1e30f

// ======================================================================
// MALL-coherent access helpers: relaxed agent-scope atomics bypass the
// (non-cross-coherent) per-XCD L2s. Used ONLY for inter-phase arrays.
// Weights / inputs keep normal cached loads -> L2 stays hot (no fences).
// ======================================================================
__device__ __forceinline__ float ld_ag(const float* p) {
  return __hip_atomic_load((float*)p, __ATOMIC_RELAXED, __HIP_MEMORY_SCOPE_AGENT);
}
__device__ __forceinline__ void st_ag(float* p, float v) {
  __hip_atomic_store(p, v, __ATOMIC_RELAXED, __HIP_MEMORY_SCOPE_AGENT);
}
__device__ __forceinline__ float4 ld4_ag(const float* p) {
  float4 r; r.x = ld_ag(p); r.y = ld_ag(p + 1); r.z = ld_ag(p + 2); r.w = ld_ag(p + 3);
  return r;
}
__device__ __forceinline__ void st4_ag(float* p, float4 v) {
  st_ag(p, v.x); st_ag(p + 1, v.y); st_ag(p + 2, v.z); st_ag(p + 3, v.w);
}

// Grid barrier with NO L2 writeback/invalidate: data coherence is carried
// by the agent-scope accesses above; vmcnt(0) ensures they completed.
__device__ __forceinline__ void gbar(unsigned* cnt, unsigned target)
{
  asm volatile("s_waitcnt vmcnt(0)" ::: "memory");
  __syncthreads();
  if (threadIdx.x == 0) {
    __hip_atomic_fetch_add(cnt, 1u, __ATOMIC_RELAXED, __HIP_MEMORY_SCOPE_AGENT);
    while (__hip_atomic_load(cnt, __ATOMIC_RELAXED, __HIP_MEMORY_SCOPE_AGENT) < target) {
      __builtin_amdgcn_s_sleep(2);
    }
  }
  __syncthreads();
}

// ======================================================================
// Shared GEMM compute: 128 threads, 32x64 tile, micro 4x4, K=256
// ======================================================================
__device__ __forceinline__ void gemm_compute(const float (*__restrict__ As)[36],
                                             const float (*__restrict__ Bs)[64],
                                             float acc[4][4])
{
  int tid = threadIdx.x;
  int tx = tid & 15, ty = tid >> 4;
#pragma unroll 8
  for (int k = 0; k < 256; ++k) {
    float4 a  = *(const float4*)&As[k][ty * 4];
    float4 bv = *(const float4*)&Bs[k][tx * 4];
    acc[0][0] = fmaf(a.x, bv.x, acc[0][0]); acc[0][1] = fmaf(a.x, bv.y, acc[0][1]);
    acc[0][2] = fmaf(a.x, bv.z, acc[0][2]); acc[0][3] = fmaf(a.x, bv.w, acc[0][3]);
    acc[1][0] = fmaf(a.y, bv.x, acc[1][0]); acc[1][1] = fmaf(a.y, bv.y, acc[1][1]);
    acc[1][2] = fmaf(a.y, bv.z, acc[1][2]); acc[1][3] = fmaf(a.y, bv.w, acc[1][3]);
    acc[2][0] = fmaf(a.z, bv.x, acc[2][0]); acc[2][1] = fmaf(a.z, bv.y, acc[2][1]);
    acc[2][2] = fmaf(a.z, bv.z, acc[2][2]); acc[2][3] = fmaf(a.z, bv.w, acc[2][3]);
    acc[3][0] = fmaf(a.w, bv.x, acc[3][0]); acc[3][1] = fmaf(a.w, bv.y, acc[3][1]);
    acc[3][2] = fmaf(a.w, bv.z, acc[3][2]); acc[3][3] = fmaf(a.w, bv.w, acc[3][3]);
  }
}

// ---------------- 256-thread staging ----------------
__device__ __forceinline__ void stageB_256(const float* __restrict__ Bw, int ldb, int n0,
                                           float (*__restrict__ Bs)[64])
{
  int tid = threadIdx.x;
#pragma unroll
  for (int i = 0; i < 16; ++i) {
    int idx = tid + 256 * i;
    int k = idx >> 4, c = (idx & 15) << 2;
    *(float4*)&Bs[k][c] = *(const float4*)(Bw + (size_t)k * ldb + n0 + c);
  }
}

// plain (cached) A-copy — for read-only inputs
__device__ __forceinline__ void stageA_ln_256(const float* __restrict__ Xsrc, int m0,
                                              const float* __restrict__ g,
                                              const float* __restrict__ b,
                                              float (*__restrict__ As)[36])
{
  int tid = threadIdx.x;
  int r = tid >> 3, p = tid & 7;
  const float* row = Xsrc + (size_t)(m0 + r) * DMODEL + p * 32;
  float4 v[8];
  float s = 0.f, ss = 0.f;
#pragma unroll
  for (int j = 0; j < 8; ++j) {
    v[j] = *(const float4*)(row + j * 4);
    s  += v[j].x + v[j].y + v[j].z + v[j].w;
    ss += v[j].x * v[j].x + v[j].y * v[j].y + v[j].z * v[j].z + v[j].w * v[j].w;
  }
  s  += __shfl_xor(s, 1);  s  += __shfl_xor(s, 2);  s  += __shfl_xor(s, 4);
  ss += __shfl_xor(ss, 1); ss += __shfl_xor(ss, 2); ss += __shfl_xor(ss, 4);
  float mean = s * (1.0f / 256.0f);
  float var  = ss * (1.0f / 256.0f) - mean * mean;
  float rstd = rsqrtf(var + 1e-5f);
#pragma unroll
  for (int j = 0; j < 8; ++j) {
    float4 gg = *(const float4*)(g + p * 32 + j * 4);
    float4 bb = *(const float4*)(b + p * 32 + j * 4);
    int k = p * 32 + j * 4;
    As[k + 0][r] = (v[j].x - mean) * rstd * gg.x + bb.x;
    As[k + 1][r] = (v[j].y - mean) * rstd * gg.y + bb.y;
    As[k + 2][r] = (v[j].z - mean) * rstd * gg.z + bb.z;
    As[k + 3][r] = (v[j].w - mean) * rstd * gg.w + bb.w;
  }
}

// agent-scope variants — for inter-phase arrays
__device__ __forceinline__ void stageA_ln_256_ag(const float* __restrict__ Xsrc, int m0,
                                                 const float* __restrict__ g,
                                                 const float* __restrict__ b,
                                                 float (*__restrict__ As)[36])
{
  int tid = threadIdx.x;
  int r = tid >> 3, p = tid & 7;
  const float* row = Xsrc + (size_t)(m0 + r) * DMODEL + p * 32;
  float4 v[8];
  float s = 0.f, ss = 0.f;
#pragma unroll
  for (int j = 0; j < 8; ++j) {
    v[j] = ld4_ag(row + j * 4);
    s  += v[j].x + v[j].y + v[j].z + v[j].w;
    ss += v[j].x * v[j].x + v[j].y * v[j].y + v[j].z * v[j].z + v[j].w * v[j].w;
  }
  s  += __shfl_xor(s, 1);  s  += __shfl_xor(s, 2);  s  += __shfl_xor(s, 4);
  ss += __shfl_xor(ss, 1); ss += __shfl_xor(ss, 2); ss += __shfl_xor(ss, 4);
  float mean = s * (1.0f / 256.0f);
  float var  = ss * (1.0f / 256.0f) - mean * mean;
  float rstd = rsqrtf(var + 1e-5f);
#pragma unroll
  for (int j = 0; j < 8; ++j) {
    float4 gg = *(const float4*)(g + p * 32 + j * 4);
    float4 bb = *(const float4*)(b + p * 32 + j * 4);
    int k = p * 32 + j * 4;
    As[k + 0][r] = (v[j].x - mean) * rstd * gg.x + bb.x;
    As[k + 1][r] = (v[j].y - mean) * rstd * gg.y + bb.y;
    As[k + 2][r] = (v[j].z - mean) * rstd * gg.z + bb.z;
    As[k + 3][r] = (v[j].w - mean) * rstd * gg.w + bb.w;
  }
}

__device__ __forceinline__ void stageA_copy_256_ag(const float* __restrict__ A, int lda,
                                                   int m0, int kbeg,
                                                   float (*__restrict__ As)[36])
{
  int tid = threadIdx.x;
  int r = tid >> 3, p = tid & 7;
  const float* row = A + (size_t)(m0 + r) * lda + kbeg + p * 32;
#pragma unroll
  for (int j = 0; j < 8; ++j) {
    float4 v = ld4_ag(row + j * 4);
    int k = p * 32 + j * 4;
    As[k + 0][r] = v.x; As[k + 1][r] = v.y; As[k + 2][r] = v.z; As[k + 3][r] = v.w;
  }
}

// ======================================================================
// Megakernel: 256 blocks x 256 threads, fence-free barriers,
// MALL-coherent inter-phase data. Phase bodies = verified round-2 code.
// ======================================================================
struct MegaParams {
  const float* src; const float* tgt; const float* rpe;
  const int* smask; const int* tmask;
  const float* ln1g; const float* ln1b; const float* lntg; const float* lntb;
  const float* ln2g; const float* ln2b;
  const float* wq; const float* bq; const float* wk; const float* bk;
  const float* wv; const float* bv; const float* wo; const float* bo;
  const float* wr; const float* br; const float* w1; const float* b1;
  const float* w2; const float* b2;
  float* out; float* Qb; float* Kb; float* Vb; float* AO; float* X; float* SRC1; float* H1;
  unsigned* bar;
};

__global__ __launch_bounds__(256) void mega_kernel(MegaParams p)
{
  __shared__ __align__(16) float smem[25600];   // 102.4 KB union
  float (*As)[36]  = reinterpret_cast<float (*)[36]>(smem);
  float (*Bs)[64]  = reinterpret_cast<float (*)[64]>(smem + 9216);
  float (*Ks)[32]  = reinterpret_cast<float (*)[32]>(smem);
  float (*Vt)[260] = reinterpret_cast<float (*)[260]>(smem + 8192);
  float (*ps)[256] = reinterpret_cast<float (*)[256]>(smem + 16512);
  float (*qs)[32]  = reinterpret_cast<float (*)[32]>(smem + 17536);
  float (*wks)[32] = reinterpret_cast<float (*)[32]>(smem + 18048);
  float (*wvs)[32] = reinterpret_cast<float (*)[32]>(smem + 18208);
  int bid = blockIdx.x, tid = threadIdx.x;
  unsigned step = 0;

  for (int l = 0; l < 2; ++l) {
    const float* srcin = l ? p.SRC1 : p.src;
    const bool srcin_ag = (l != 0);          // SRC1 is inter-phase; src is input
    float* outb = l ? p.out : p.SRC1;
    const float* wq = p.wq + l * 65536;  const float* bq = p.bq + l * 256;
    const float* wk = p.wk + l * 65536;  const float* bk = p.bk + l * 256;
    const float* wv = p.wv + l * 65536;  const float* bv = p.bv + l * 256;
    const float* wo = p.wo + l * 65536;  const float* bo = p.bo + l * 256;
    const float* wr = p.wr + l * 2048;   const float* br = p.br + l * 512;
    const float* w1 = p.w1 + l * 262144; const float* b1 = p.b1 + l * 1024;
    const float* w2 = p.w2 + l * 262144; const float* b2 = p.b2 + l * 256;
    const float* ln1g = p.ln1g + l * 256; const float* ln1b = p.ln1b + l * 256;
    const float* lntg = p.lntg + l * 256; const float* lntb = p.lntb + l * 256;
    const float* ln2g = p.ln2g + l * 256; const float* ln2b = p.ln2b + l * 256;

    // ===== phase 1: QKV (192 tasks) =====
    if (bid < 192) {
      int x = bid & 3, y = (bid >> 2) & 15, z = bid >> 6;
      int m0 = y * 32, n0 = x * 64;
      const float* Bw = (z == 0) ? wq : (z == 1) ? wk : wv;
      stageB_256(Bw, DMODEL, n0, Bs);
      if (z == 0) {
        if (srcin_ag) stageA_ln_256_ag(srcin, m0, ln1g, ln1b, As);
        else          stageA_ln_256(srcin, m0, ln1g, ln1b, As);
      } else {
        stageA_ln_256(p.tgt, m0, lntg, lntb, As);
      }
      __syncthreads();
      if (tid < 128) {
        float acc[4][4] = {};
        gemm_compute(As, Bs, acc);
        const float* bias = (z == 0) ? bq : (z == 1) ? bk : bv;
        int tx = tid & 15, ty = tid >> 4;
        int c0 = n0 + tx * 4;
        float4 bias4 = *(const float4*)(bias + c0);
        const float scale = 0.1767766952966369f;  // 1/sqrt(32)
#pragma unroll
        for (int i = 0; i < 4; ++i) {
          int m = m0 + ty * 4 + i;
          float4 r;
          r.x = acc[i][0] + bias4.x;
          r.y = acc[i][1] + bias4.y;
          r.z = acc[i][2] + bias4.z;
          r.w = acc[i][3] + bias4.w;
          if (z == 0) {
            r.x *= scale; r.y *= scale; r.z *= scale; r.w *= scale;
            st4_ag(&p.Qb[m * DMODEL + c0], r);
          } else {
            int b_ = m >> 8, t = m & 255, h = c0 >> 5, d0 = c0 & 31;
            float* dst = ((z == 1) ? p.Kb : p.Vb) + (size_t)(b_ * NH + h) * 8192 + t * DH + d0;
            st4_ag(dst, r);
          }
        }
      }
    }
    gbar(p.bar, ++step * 256u);

    // ===== phase 2: attention (256 tasks) =====
    {
      int ab = bid >> 7, h = (bid >> 4) & 7, s0 = (bid & 15) << 4;
      const float* Kp = p.Kb + (size_t)(ab * NH + h) * 8192;
      const float* Vp = p.Vb + (size_t)(ab * NH + h) * 8192;
      {
        int t = tid;
        int sw = t & 7;
#pragma unroll
        for (int c = 0; c < 8; ++c) {
          float4 k4 = ld4_ag(Kp + t * DH + c * 4);
          *(float4*)&Ks[t][(c ^ sw) * 4] = k4;
        }
#pragma unroll
        for (int c = 0; c < 8; ++c) {
          float4 v4 = ld4_ag(Vp + t * DH + c * 4);
          Vt[c*4+0][t] = v4.x; Vt[c*4+1][t] = v4.y; Vt[c*4+2][t] = v4.z; Vt[c*4+3][t] = v4.w;
        }
      }
      if (tid < 160) {
        int j = tid >> 5, d = tid & 31;
        wks[j][d] = (j < 4) ? wr[j * 512 + h * DH + d]       : br[h * DH + d];
        wvs[j][d] = (j < 4) ? wr[j * 512 + 256 + h * DH + d] : br[256 + h * DH + d];
      }
      if (tid >= 128) {
        int u = tid - 128;
        int rr_ = u >> 3, cc = u & 7;
        float4 qv = ld4_ag(&p.Qb[(ab * 256 + s0 + rr_) * DMODEL + h * DH + cc * 4]);
        *(float4*)&qs[rr_][cc*4] = qv;
      }
      __syncthreads();

      int w = tid >> 6, lane = tid & 63;
      int msk[4];
#pragma unroll
      for (int it = 0; it < 4; ++it) msk[it] = p.tmask[ab * 256 + it * 64 + lane];

      for (int i = 0; i < 4; ++i) {
        int sl = w * 4 + i;
        int s = s0 + sl;
        float4 q4[8];
#pragma unroll
        for (int c = 0; c < 8; ++c) q4[c] = *(const float4*)&qs[sl][c * 4];
        float qw[4]; float qbr = 0.0f;
#pragma unroll
        for (int j = 0; j < 4; ++j) {
          float t0 = 0;
#pragma unroll
          for (int c = 0; c < 8; ++c) {
            float4 wv4 = *(const float4*)&wks[j][c * 4];
            t0 += q4[c].x*wv4.x + q4[c].y*wv4.y + q4[c].z*wv4.z + q4[c].w*wv4.w;
          }
          qw[j] = t0;
        }
#pragma unroll
        for (int c = 0; c < 8; ++c) {
          float4 wv4 = *(const float4*)&wks[4][c * 4];
          qbr += q4[c].x*wv4.x + q4[c].y*wv4.y + q4[c].z*wv4.z + q4[c].w*wv4.w;
        }
        const float4* rp4 = (const float4*)(p.rpe + (size_t)(ab * 256 + s) * 1024);
        float sc[4]; float4 rr[4];
#pragma unroll
        for (int it = 0; it < 4; ++it) {
          int t = it * 64 + lane;
          int sw = t & 7;
          float sv = 0;
#pragma unroll
          for (int c = 0; c < 8; ++c) {
            float4 k4 = *(const float4*)&Ks[t][(c ^ sw) * 4];
            sv = fmaf(q4[c].x, k4.x, sv); sv = fmaf(q4[c].y, k4.y, sv);
            sv = fmaf(q4[c].z, k4.z, sv); sv = fmaf(q4[c].w, k4.w, sv);
          }
          float4 rv = rp4[t];
          rr[it] = rv;
          sv += rv.x*qw[0] + rv.y*qw[1] + rv.z*qw[2] + rv.w*qw[3] + qbr;
          if (msk[it] != 0) sv = NEG_INF;
          sc[it] = sv;
        }
        float mval = fmaxf(fmaxf(sc[0], sc[1]), fmaxf(sc[2], sc[3]));
#pragma unroll
        for (int off = 32; off >= 1; off >>= 1) mval = fmaxf(mval, __shfl_xor(mval, off));
        float pr[4], lsum = 0;
#pragma unroll
        for (int it = 0; it < 4; ++it) { pr[it] = __expf(sc[it] - mval); lsum += pr[it]; }
        float wj0 = 0, wj1 = 0, wj2 = 0, wj3 = 0;
#pragma unroll
        for (int it = 0; it < 4; ++it) {
          wj0 = fmaf(pr[it], rr[it].x, wj0);
          wj1 = fmaf(pr[it], rr[it].y, wj1);
          wj2 = fmaf(pr[it], rr[it].z, wj2);
          wj3 = fmaf(pr[it], rr[it].w, wj3);
        }
#pragma unroll
        for (int off = 32; off >= 1; off >>= 1) {
          lsum += __shfl_xor(lsum, off);
          wj0 += __shfl_xor(wj0, off);
          wj1 += __shfl_xor(wj1, off);
          wj2 += __shfl_xor(wj2, off);
          wj3 += __shfl_xor(wj3, off);
        }
#pragma unroll
        for (int it = 0; it < 4; ++it) ps[w][it * 64 + lane] = pr[it];
        int g = lane >> 5, d = lane & 31;
        float o = 0;
#pragma unroll
        for (int n = 0; n < 32; ++n) {
          int t = g * 128 + n * 4;
          float4 p4 = *(const float4*)&ps[w][t];
          float4 v4 = *(const float4*)&Vt[d][t];
          o += p4.x*v4.x + p4.y*v4.y + p4.z*v4.z + p4.w*v4.w;
        }
        o += __shfl_xor(o, 32);
        float corr = wj0 * wvs[0][d] + wj1 * wvs[1][d] + wj2 * wvs[2][d] + wj3 * wvs[3][d];
        float oval = (o + corr) / lsum + wvs[4][d];
        if (lane < 32) st_ag(&p.AO[(ab * 256 + s) * DMODEL + h * DH + d], oval);
      }
    }
    gbar(p.bar, ++step * 256u);

    // ===== phase 3: wo + residual (64 tasks) =====
    if (bid < 64) {
      int x = bid & 3, y = bid >> 2;
      int m0 = y * 32, n0 = x * 64;
      stageB_256(wo, DMODEL, n0, Bs);
      stageA_copy_256_ag(p.AO, DMODEL, m0, 0, As);
      __syncthreads();
      if (tid < 128) {
        float acc[4][4] = {};
        gemm_compute(As, Bs, acc);
        int tx = tid & 15, ty = tid >> 4;
        int c0 = n0 + tx * 4;
        float4 bov = *(const float4*)(bo + c0);
#pragma unroll
        for (int i = 0; i < 4; ++i) {
          int m = m0 + ty * 4 + i;
          float4 sv = srcin_ag ? ld4_ag(srcin + (size_t)m * DMODEL + c0)
                               : *(const float4*)(srcin + (size_t)m * DMODEL + c0);
          float4 r;
          r.x = sv.x + bov.x + acc[i][0];
          r.y = sv.y + bov.y + acc[i][1];
          r.z = sv.z + bov.z + acc[i][2];
          r.w = sv.w + bov.w + acc[i][3];
          st4_ag(&p.X[(size_t)m * DMODEL + c0], r);
        }
      }
    }
    gbar(p.bar, ++step * 256u);

    // ===== phase 4: FF1 + LN2 + ReLU; x==0 writes out-init (256 tasks) =====
    {
      int x = bid & 15, y = bid >> 4;
      int m0 = y * 32, n0 = x * 64;
      stageB_256(w1, 1024, n0, Bs);
      stageA_ln_256_ag(p.X, m0, ln2g, ln2b, As);
      if (x == 0 && tid < 128) {
        int r = tid >> 2, pq = tid & 3;
        int m = m0 + r;
        float mm = (p.smask[m] != 0) ? 0.0f : 1.0f;
#pragma unroll
        for (int j = 0; j < 16; ++j) {
          float4 xv  = ld4_ag(p.X + (size_t)m * DMODEL + pq * 64 + j * 4);
          float4 b2v = *(const float4*)(b2 + pq * 64 + j * 4);
          float4 o;
          o.x = mm * (xv.x + b2v.x); o.y = mm * (xv.y + b2v.y);
          o.z = mm * (xv.z + b2v.z); o.w = mm * (xv.w + b2v.w);
          st4_ag(outb + (size_t)m * DMODEL + pq * 64 + j * 4, o);
        }
      }
      __syncthreads();
      if (tid < 128) {
        float acc[4][4] = {};
        gemm_compute(As, Bs, acc);
        int tx = tid & 15, ty = tid >> 4;
        int c0 = n0 + tx * 4;
        float4 b1v = *(const float4*)(b1 + c0);
#pragma unroll
        for (int i = 0; i < 4; ++i) {
          int m = m0 + ty * 4 + i;
          float4 r;
          r.x = fmaxf(acc[i][0] + b1v.x, 0.0f);
          r.y = fmaxf(acc[i][1] + b1v.y, 0.0f);
          r.z = fmaxf(acc[i][2] + b1v.z, 0.0f);
          r.w = fmaxf(acc[i][3] + b1v.w, 0.0f);
          st4_ag(&p.H1[(size_t)m * 1024 + c0], r);
        }
      }
    }
    gbar(p.bar, ++step * 256u);

    // ===== phase 5: FF2 split-K=4, masked atomic accumulate (256 tasks) =====
    {
      int x = bid & 3, y = (bid >> 2) & 15, z = bid >> 6;
      int m0 = y * 32, n0 = x * 64;
      int kbeg = z * 256;
      stageB_256(w2 + (size_t)kbeg * DMODEL, DMODEL, n0, Bs);
      stageA_copy_256_ag(p.H1, 1024, m0, kbeg, As);
      __syncthreads();
      if (tid < 128) {
        float acc[4][4] = {};
        gemm_compute(As, Bs, acc);
        int tx = tid & 15, ty = tid >> 4;
        int c0 = n0 + tx * 4;
#pragma unroll
        for (int i = 0; i < 4; ++i) {
          int m = m0 + ty * 4 + i;
          if (p.smask[m] == 0) {
            atomicAdd(&outb[(size_t)m * DMODEL + c0 + 0], acc[i][0]);
            atomicAdd(&outb[(size_t)m * DMODEL + c0 + 1], acc[i][1]);
            atomicAdd(&outb[(size_t)m * DMODEL + c0 + 2], acc[i][2]);
            atomicAdd(&outb[(size_t)m * DMODEL + c0 + 3], acc[i][3]);
          }
        }
      }
    }
    if (l == 0) gbar(p.bar, ++step * 256u);
  }
}

// ======================================================================
// Fallback: verified round-2 split kernels (used if cooperative launch fails)
// ======================================================================
__device__ __forceinline__ void stage_B64(const float* __restrict__ Bw, int ldb, int n0,
                                          float (*__restrict__ Bs)[64])
{
  int tid = threadIdx.x;
#pragma unroll
  for (int i = 0; i < 32; ++i) {
    int idx = tid + 128 * i;
    int k = idx >> 4, c = (idx & 15) << 2;
    *(float4*)&Bs[k][c] = *(const float4*)(Bw + (size_t)k * ldb + n0 + c);
  }
}

__device__ __forceinline__ void stage_A_copy(const float* __restrict__ A, int lda,
                                             int m0, int kbeg,
                                             float (*__restrict__ As)[36])
{
  int tid = threadIdx.x;
  int r = tid >> 2, p = tid & 3;
  const float* row = A + (size_t)(m0 + r) * lda + kbeg + p * 64;
#pragma unroll
  for (int j = 0; j < 16; ++j) {
    float4 v = *(const float4*)(row + j * 4);
    int k = p * 64 + j * 4;
    As[k + 0][r] = v.x; As[k + 1][r] = v.y; As[k + 2][r] = v.z; As[k + 3][r] = v.w;
  }
}

__device__ __forceinline__ void stage_A_ln(const float* __restrict__ Xsrc, int m0,
                                           const float* __restrict__ g,
                                           const float* __restrict__ b,
                                           float (*__restrict__ As)[36])
{
  int tid = threadIdx.x;
  int r = tid >> 2, p = tid & 3;
  const float* row = Xsrc + (size_t)(m0 + r) * DMODEL + p * 64;
  float4 v[16];
  float s = 0.f, ss = 0.f;
#pragma unroll
  for (int j = 0; j < 16; ++j) {
    v[j] = *(const float4*)(row + j * 4);
    s  += v[j].x + v[j].y + v[j].z + v[j].w;
    ss += v[j].x * v[j].x + v[j].y * v[j].y + v[j].z * v[j].z + v[j].w * v[j].w;
  }
  s  += __shfl_xor(s, 1);  s  += __shfl_xor(s, 2);
  ss += __shfl_xor(ss, 1); ss += __shfl_xor(ss, 2);
  float mean = s * (1.0f / 256.0f);
  float var  = ss * (1.0f / 256.0f) - mean * mean;
  float rstd = rsqrtf(var + 1e-5f);
#pragma unroll
  for (int j = 0; j < 16; ++j) {
    float4 gg = *(const float4*)(g + p * 64 + j * 4);
    float4 bb = *(const float4*)(b + p * 64 + j * 4);
    int k = p * 64 + j * 4;
    As[k + 0][r] = (v[j].x - mean) * rstd * gg.x + bb.x;
    As[k + 1][r] = (v[j].y - mean) * rstd * gg.y + bb.y;
    As[k + 2][r] = (v[j].z - mean) * rstd * gg.z + bb.z;
    As[k + 3][r] = (v[j].w - mean) * rstd * gg.w + bb.w;
  }
}

__global__ __launch_bounds__(128) void qkv_kernel(
    const float* __restrict__ srcin, const float* __restrict__ tgt,
    const float* __restrict__ ln1g, const float* __restrict__ ln1b,
    const float* __restrict__ lntg, const float* __restrict__ lntb,
    const float* __restrict__ wq, const float* __restrict__ wk, const float* __restrict__ wv,
    const float* __restrict__ bq, const float* __restrict__ bk, const float* __restrict__ bv,
    float* __restrict__ Qb, float* __restrict__ Kb, float* __restrict__ Vb)
{
  __shared__ __align__(16) float As[256][36];
  __shared__ __align__(16) float Bs[256][64];
  int z = blockIdx.z;
  int m0 = blockIdx.y * 32, n0 = blockIdx.x * 64;
  const float* Bw = (z == 0) ? wq : (z == 1) ? wk : wv;
  stage_B64(Bw, DMODEL, n0, Bs);
  if (z == 0) stage_A_ln(srcin, m0, ln1g, ln1b, As);
  else        stage_A_ln(tgt,   m0, lntg, lntb, As);
  __syncthreads();
  float acc[4][4] = {};
  gemm_compute(As, Bs, acc);
  const float* bias = (z == 0) ? bq : (z == 1) ? bk : bv;
  int tid = threadIdx.x, tx = tid & 15, ty = tid >> 4;
  int c0 = n0 + tx * 4;
  float4 bias4 = *(const float4*)(bias + c0);
  const float scale = 0.1767766952966369f;
#pragma unroll
  for (int i = 0; i < 4; ++i) {
    int m = m0 + ty * 4 + i;
    float4 r;
    r.x = acc[i][0] + bias4.x;
    r.y = acc[i][1] + bias4.y;
    r.z = acc[i][2] + bias4.z;
    r.w = acc[i][3] + bias4.w;
    if (z == 0) {
      r.x *= scale; r.y *= scale; r.z *= scale; r.w *= scale;
      *(float4*)&Qb[m * DMODEL + c0] = r;
    } else {
      int b = m >> 8, t = m & 255, h = c0 >> 5, d0 = c0 & 31;
      float* dst = ((z == 1) ? Kb : Vb) + (size_t)(b * NH + h) * 8192 + t * DH + d0;
      *(float4*)dst = r;
    }
  }
}

__global__ __launch_bounds__(128) void wo_kernel(
    const float* __restrict__ AO, const float* __restrict__ wo,
    const float* __restrict__ srcin, const float* __restrict__ bo,
    float* __restrict__ X)
{
  __shared__ __align__(16) float As[256][36];
  __shared__ __align__(16) float Bs[256][64];
  int m0 = blockIdx.y * 32, n0 = blockIdx.x * 64;
  stage_B64(wo, DMODEL, n0, Bs);
  stage_A_copy(AO, DMODEL, m0, 0, As);
  __syncthreads();
  float acc[4][4] = {};
  gemm_compute(As, Bs, acc);
  int tid = threadIdx.x, tx = tid & 15, ty = tid >> 4;
  int c0 = n0 + tx * 4;
  float4 bov = *(const float4*)(bo + c0);
#pragma unroll
  for (int i = 0; i < 4; ++i) {
    int m = m0 + ty * 4 + i;
    float4 sv = *(const float4*)(srcin + (size_t)m * DMODEL + c0);
    float4 r;
    r.x = sv.x + bov.x + acc[i][0];
    r.y = sv.y + bov.y + acc[i][1];
    r.z = sv.z + bov.z + acc[i][2];
    r.w = sv.w + bov.w + acc[i][3];
    *(float4*)&X[(size_t)m * DMODEL + c0] = r;
  }
}

__global__ __launch_bounds__(128) void ff1_kernel(
    const float* __restrict__ X, const float* __restrict__ ln2g, const float* __restrict__ ln2b,
    const float* __restrict__ w1, const float* __restrict__ b1,
    const float* __restrict__ b2, const int* __restrict__ smask,
    float* __restrict__ H1, float* __restrict__ outb)
{
  __shared__ __align__(16) float As[256][36];
  __shared__ __align__(16) float Bs[256][64];
  int m0 = blockIdx.y * 32, n0 = blockIdx.x * 64;
  stage_B64(w1, 1024, n0, Bs);
  stage_A_ln(X, m0, ln2g, ln2b, As);
  if (blockIdx.x == 0) {
    int tid = threadIdx.x;
    int r = tid >> 2, p = tid & 3;
    int m = m0 + r;
    float mm = (smask[m] != 0) ? 0.0f : 1.0f;
#pragma unroll
    for (int j = 0; j < 16; ++j) {
      float4 xv  = *(const float4*)(X  + (size_t)m * DMODEL + p * 64 + j * 4);
      float4 b2v = *(const float4*)(b2 + p * 64 + j * 4);
      float4 o;
      o.x = mm * (xv.x + b2v.x); o.y = mm * (xv.y + b2v.y);
      o.z = mm * (xv.z + b2v.z); o.w = mm * (xv.w + b2v.w);
      *(float4*)(outb + (size_t)m * DMODEL + p * 64 + j * 4) = o;
    }
  }
  __syncthreads();
  float acc[4][4] = {};
  gemm_compute(As, Bs, acc);
  int tid = threadIdx.x, tx = tid & 15, ty = tid >> 4;
  int c0 = n0 + tx * 4;
  float4 b1v = *(const float4*)(b1 + c0);
#pragma unroll
  for (int i = 0; i < 4; ++i) {
    int m = m0 + ty * 4 + i;
    float4 r;
    r.x = fmaxf(acc[i][0] + b1v.x, 0.0f);
    r.y = fmaxf(acc[i][1] + b1v.y, 0.0f);
    r.z = fmaxf(acc[i][2] + b1v.z, 0.0f);
    r.w = fmaxf(acc[i][3] + b1v.w, 0.0f);
    *(float4*)&H1[(size_t)m * 1024 + c0] = r;
  }
}

__global__ __launch_bounds__(128) void ff2_kernel(
    const float* __restrict__ H1, const float* __restrict__ w2,
    const int* __restrict__ smask, float* __restrict__ outb)
{
  __shared__ __align__(16) float As[256][36];
  __shared__ __align__(16) float Bs[256][64];
  int m0 = blockIdx.y * 32, n0 = blockIdx.x * 64;
  int kbeg = blockIdx.z * 256;
  stage_B64(w2 + (size_t)kbeg * DMODEL, DMODEL, n0, Bs);
  stage_A_copy(H1, 1024, m0, kbeg, As);
  __syncthreads();
  float acc[4][4] = {};
  gemm_compute(As, Bs, acc);
  int tid = threadIdx.x, tx = tid & 15, ty = tid >> 4;
  int c0 = n0 + tx * 4;
#pragma unroll
  for (int i = 0; i < 4; ++i) {
    int m = m0 + ty * 4 + i;
    if (smask[m] == 0) {
      atomicAdd(&outb[(size_t)m * DMODEL + c0 + 0], acc[i][0]);
      atomicAdd(&outb[(size_t)m * DMODEL + c0 + 1], acc[i][1]);
      atomicAdd(&outb[(size_t)m * DMODEL + c0 + 2], acc[i][2]);
      atomicAdd(&outb[(size_t)m * DMODEL + c0 + 3], acc[i][3]);
    }
  }
}

__global__ __launch_bounds__(256) void attn_kernel(
    const float* __restrict__ Qb, const float* __restrict__ Kb, const float* __restrict__ Vb,
    const float* __restrict__ rpe, const int* __restrict__ tmask,
    const float* __restrict__ wrl, const float* __restrict__ brl,
    float* __restrict__ AO)
{
  __shared__ float Ks[256][32];
  __shared__ float Vt[32][260];
  __shared__ float ps[4][256];
  __shared__ float qs[16][32];
  __shared__ float wks[5][32];
  __shared__ float wvs[5][32];
  int bid = blockIdx.x;
  int b = bid >> 7, h = (bid >> 4) & 7, s0 = (bid & 15) << 4;
  int tid = threadIdx.x;
  const float* Kp = Kb + (size_t)(b * NH + h) * 8192;
  const float* Vp = Vb + (size_t)(b * NH + h) * 8192;
  {
    int t = tid;
    const float4* kr = (const float4*)(Kp + t * DH);
    const float4* vr = (const float4*)(Vp + t * DH);
    int sw = t & 7;
#pragma unroll
    for (int c = 0; c < 8; ++c) {
      float4 k4 = kr[c];
      *(float4*)&Ks[t][(c ^ sw) * 4] = k4;
    }
#pragma unroll
    for (int c = 0; c < 8; ++c) {
      float4 v4 = vr[c];
      Vt[c*4+0][t] = v4.x; Vt[c*4+1][t] = v4.y; Vt[c*4+2][t] = v4.z; Vt[c*4+3][t] = v4.w;
    }
  }
  if (tid < 160) {
    int j = tid >> 5, d = tid & 31;
    wks[j][d] = (j < 4) ? wrl[j * 512 + h * DH + d]       : brl[h * DH + d];
    wvs[j][d] = (j < 4) ? wrl[j * 512 + 256 + h * DH + d] : brl[256 + h * DH + d];
  }
  if (tid >= 128) {
    int u = tid - 128;
    int rr = u >> 3, cc = u & 7;
    *(float4*)&qs[rr][cc*4] =
        *(const float4*)&Qb[(b * 256 + s0 + rr) * DMODEL + h * DH + cc * 4];
  }
  __syncthreads();

  int w = tid >> 6, lane = tid & 63;
  int msk[4];
#pragma unroll
  for (int it = 0; it < 4; ++it) msk[it] = tmask[b * 256 + it * 64 + lane];

  for (int i = 0; i < 4; ++i) {
    int sl = w * 4 + i;
    int s = s0 + sl;
    float4 q4[8];
#pragma unroll
    for (int c = 0; c < 8; ++c) q4[c] = *(const float4*)&qs[sl][c * 4];
    float qw[4]; float qbr = 0.0f;
#pragma unroll
    for (int j = 0; j < 4; ++j) {
      float t0 = 0;
#pragma unroll
      for (int c = 0; c < 8; ++c) {
        float4 wv4 = *(const float4*)&wks[j][c * 4];
        t0 += q4[c].x*wv4.x + q4[c].y*wv4.y + q4[c].z*wv4.z + q4[c].w*wv4.w;
      }
      qw[j] = t0;
    }
#pragma unroll
    for (int c = 0; c < 8; ++c) {
      float4 wv4 = *(const float4*)&wks[4][c * 4];
      qbr += q4[c].x*wv4.x + q4[c].y*wv4.y + q4[c].z*wv4.z + q4[c].w*wv4.w;
    }
    const float4* rp4 = (const float4*)(rpe + (size_t)(b * 256 + s) * 1024);
    float sc[4]; float4 rr[4];
#pragma unroll
    for (int it = 0; it < 4; ++it) {
      int t = it * 64 + lane;
      int sw = t & 7;
      float sv = 0;
#pragma unroll
      for (int c = 0; c < 8; ++c) {
        float4 k4 = *(const float4*)&Ks[t][(c ^ sw) * 4];
        sv = fmaf(q4[c].x, k4.x, sv); sv = fmaf(q4[c].y, k4.y, sv);
        sv = fmaf(q4[c].z, k4.z, sv); sv = fmaf(q4[c].w, k4.w, sv);
      }
      float4 rv = rp4[t];
      rr[it] = rv;
      sv += rv.x*qw[0] + rv.y*qw[1] + rv.z*qw[2] + rv.w*qw[3] + qbr;
      if (msk[it] != 0) sv = NEG_INF;
      sc[it] = sv;
    }
    float mval = fmaxf(fmaxf(sc[0], sc[1]), fmaxf(sc[2], sc[3]));
#pragma unroll
    for (int off = 32; off >= 1; off >>= 1) mval = fmaxf(mval, __shfl_xor(mval, off));
    float p[4], lsum = 0;
#pragma unroll
    for (int it = 0; it < 4; ++it) { p[it] = __expf(sc[it] - mval); lsum += p[it]; }
    float wj0 = 0, wj1 = 0, wj2 = 0, wj3 = 0;
#pragma unroll
    for (int it = 0; it < 4; ++it) {
      wj0 = fmaf(p[it], rr[it].x, wj0);
      wj1 = fmaf(p[it], rr[it].y, wj1);
      wj2 = fmaf(p[it], rr[it].z, wj2);
      wj3 = fmaf(p[it], rr[it].w, wj3);
    }
#pragma unroll
    for (int off = 32; off >= 1; off >>= 1) {
      lsum += __shfl_xor(lsum, off);
      wj0 += __shfl_xor(wj0, off);
      wj1 += __shfl_xor(wj1, off);
      wj2 += __shfl_xor(wj2, off);
      wj3 += __shfl_xor(wj3, off);
    }
#pragma unroll
    for (int it = 0; it < 4; ++it) ps[w][it * 64 + lane] = p[it];
    int g = lane >> 5, d = lane & 31;
    float o = 0;
#pragma unroll
    for (int n = 0; n < 32; ++n) {
      int t = g * 128 + n * 4;
      float4 p4 = *(const float4*)&ps[w][t];
      float4 v4 = *(const float4*)&Vt[d][t];
      o += p4.x*v4.x + p4.y*v4.y + p4.z*v4.z + p4.w*v4.w;
    }
    o += __shfl_xor(o, 32);
    float corr = wj0 * wvs[0][d] + wj1 * wvs[1][d] + wj2 * wvs[2][d] + wj3 * wvs[3][d];
    float oval = (o + corr) / lsum + wvs[4][d];
    if (lane < 32) AO[(b * 256 + s) * DMODEL + h * DH + d] = oval;
  }
}

extern "C" void kernel_launch(void* const* d_in, const int* in_sizes, int n_in,
                              void* d_out, int out_size, void* d_ws, size_t ws_size,
                              hipStream_t stream)
{
  const float* src  = (const float*)d_in[0];
  const float* tgt  = (const float*)d_in[1];
  const float* rpe  = (const float*)d_in[2];
  const int*   smask = (const int*)d_in[3];
  const int*   tmask = (const int*)d_in[4];
  const float* ln1g = (const float*)d_in[5];
  const float* ln1b = (const float*)d_in[6];
  const float* lntg = (const float*)d_in[7];
  const float* lntb = (const float*)d_in[8];
  const float* ln2g = (const float*)d_in[9];
  const float* ln2b = (const float*)d_in[10];
  const float* wq = (const float*)d_in[11];
  const float* bq = (const float*)d_in[12];
  const float* wk = (const float*)d_in[13];
  const float* bk = (const float*)d_in[14];
  const float* wv = (const float*)d_in[15];
  const float* bv = (const float*)d_in[16];
  const float* wo = (const float*)d_in[17];
  const float* bo = (const float*)d_in[18];
  const float* wr = (const float*)d_in[19];
  const float* br = (const float*)d_in[20];
  const float* w1 = (const float*)d_in[21];
  const float* b1 = (const float*)d_in[22];
  const float* w2 = (const float*)d_in[23];
  const float* b2 = (const float*)d_in[24];

  float* w    = (float*)d_ws;
  float* Qb   = w;
  float* Kb   = w + 131072;
  float* Vb   = w + 262144;
  float* AO   = w + 393216;
  float* X    = w + 524288;
  float* SRC1 = w + 655360;
  float* H1   = w + 786432;
  unsigned* bar = (unsigned*)(w + 1572864);

  MegaParams mp;
  mp.src = src; mp.tgt = tgt; mp.rpe = rpe; mp.smask = smask; mp.tmask = tmask;
  mp.ln1g = ln1g; mp.ln1b = ln1b; mp.lntg = lntg; mp.lntb = lntb;
  mp.ln2g = ln2g; mp.ln2b = ln2b;
  mp.wq = wq; mp.bq = bq; mp.wk = wk; mp.bk = bk; mp.wv = wv; mp.bv = bv;
  mp.wo = wo; mp.bo = bo; mp.wr = wr; mp.br = br;
  mp.w1 = w1; mp.b1 = b1; mp.w2 = w2; mp.b2 = b2;
  mp.out = (float*)d_out;
  mp.Qb = Qb; mp.Kb = Kb; mp.Vb = Vb; mp.AO = AO; mp.X = X; mp.SRC1 = SRC1; mp.H1 = H1;
  mp.bar = bar;

  hipMemsetAsync(bar, 0, 64, stream);

  void* args[] = { &mp };
  hipError_t err = hipLaunchCooperativeKernel((const void*)mega_kernel,
                                              dim3(256), dim3(256), args, 0, stream);
  if (err != hipSuccess) {
    (void)hipGetLastError();
    for (int l = 0; l < 2; ++l) {
      const float* srcin = l ? SRC1 : src;
      float* outb = l ? (float*)d_out : SRC1;
      qkv_kernel<<<dim3(4, 16, 3), 128, 0, stream>>>(
          srcin, tgt, ln1g + l*256, ln1b + l*256, lntg + l*256, lntb + l*256,
          wq + l*65536, wk + l*65536, wv + l*65536,
          bq + l*256, bk + l*256, bv + l*256, Qb, Kb, Vb);
      attn_kernel<<<256, 256, 0, stream>>>(Qb, Kb, Vb, rpe, tmask,
                                           wr + l*2048, br + l*512, AO);
      wo_kernel<<<dim3(4, 16), 128, 0, stream>>>(AO, wo + l*65536, srcin, bo + l*256, X);
      ff1_kernel<<<dim3(16, 16), 128, 0, stream>>>(X, ln2g + l*256, ln2b + l*256,
                                                   w1 + l*262144, b1 + l*1024,
                                                   b2 + l*256, smask, H1, outb);
      ff2_kernel<<<dim3(4, 16, 4), 128, 0, stream>>>(H1, w2 + l*262144, smask, outb);
    }
  }
}

// Round 6
// 271.930 us; speedup vs baseline: 2.2521x; 1.9888x over previous
//
#include <hip/hip_runtime.h>
#include <math.h>

#define DMODEL 256
#define NH 8
#define DH 32
#define NEG_INF -1e30f

// ======================================================================
// Chunked double-buffered GEMM: 128 thr, tile 32x64, K in chunks of 64.
// LDS = As[2][64][36] (18.4KB) + Bs[2][64][64] (32.8KB) = 50KB -> 3 blk/CU.
// Per chunk: issue next chunk's global loads -> compute -> ds_write -> sync.
// ======================================================================
__device__ __forceinline__ void gemm_chunk(const float (*__restrict__ As)[36],
                                           const float (*__restrict__ Bs)[64],
                                           float acc[4][4])
{
  int tid = threadIdx.x;
  int tx = tid & 15, ty = tid >> 4;
#pragma unroll 8
  for (int k = 0; k < 64; ++k) {
    float4 a  = *(const float4*)&As[k][ty * 4];
    float4 bv = *(const float4*)&Bs[k][tx * 4];
    acc[0][0] = fmaf(a.x, bv.x, acc[0][0]); acc[0][1] = fmaf(a.x, bv.y, acc[0][1]);
    acc[0][2] = fmaf(a.x, bv.z, acc[0][2]); acc[0][3] = fmaf(a.x, bv.w, acc[0][3]);
    acc[1][0] = fmaf(a.y, bv.x, acc[1][0]); acc[1][1] = fmaf(a.y, bv.y, acc[1][1]);
    acc[1][2] = fmaf(a.y, bv.z, acc[1][2]); acc[1][3] = fmaf(a.y, bv.w, acc[1][3]);
    acc[2][0] = fmaf(a.z, bv.x, acc[2][0]); acc[2][1] = fmaf(a.z, bv.y, acc[2][1]);
    acc[2][2] = fmaf(a.z, bv.z, acc[2][2]); acc[2][3] = fmaf(a.z, bv.w, acc[2][3]);
    acc[3][0] = fmaf(a.w, bv.x, acc[3][0]); acc[3][1] = fmaf(a.w, bv.y, acc[3][1]);
    acc[3][2] = fmaf(a.w, bv.z, acc[3][2]); acc[3][3] = fmaf(a.w, bv.w, acc[3][3]);
  }
}

// A supplied by LayerNorm over a 256-wide row held in registers.
// Thread (r=tid>>2, p=tid&3): v[j] covers k = (j>>2)*64 + p*16 + (j&3)*4.
__device__ __forceinline__ void gemm_ln(
    const float* __restrict__ Xsrc,
    const float* __restrict__ g, const float* __restrict__ b,
    const float* __restrict__ Bw, int ldb, int m0, int n0,
    float (*__restrict__ As)[64][36], float (*__restrict__ Bs)[64][64],
    float acc[4][4])
{
  int tid = threadIdx.x;
  int r = tid >> 2, p = tid & 3;
  const float* row = Xsrc + (size_t)(m0 + r) * DMODEL;
  float4 v[16];
  float s = 0.f, ss = 0.f;
#pragma unroll
  for (int j = 0; j < 16; ++j) {
    int kg = (j >> 2) * 64 + p * 16 + (j & 3) * 4;
    v[j] = *(const float4*)(row + kg);
    s  += v[j].x + v[j].y + v[j].z + v[j].w;
    ss += v[j].x * v[j].x + v[j].y * v[j].y + v[j].z * v[j].z + v[j].w * v[j].w;
  }
  s  += __shfl_xor(s, 1);  s  += __shfl_xor(s, 2);
  ss += __shfl_xor(ss, 1); ss += __shfl_xor(ss, 2);
  float mean = s * (1.0f / 256.0f);
  float var  = ss * (1.0f / 256.0f) - mean * mean;
  float rstd = rsqrtf(var + 1e-5f);
#pragma unroll
  for (int j = 0; j < 16; ++j) {   // normalize now; apply g,b at write time
    v[j].x = (v[j].x - mean) * rstd;
    v[j].y = (v[j].y - mean) * rstd;
    v[j].z = (v[j].z - mean) * rstd;
    v[j].w = (v[j].w - mean) * rstd;
  }
  // prologue: chunk 0 direct to LDS
#pragma unroll
  for (int i = 0; i < 8; ++i) {
    int idx = tid + 128 * i;
    int k = idx >> 4, c = (idx & 15) << 2;
    *(float4*)&Bs[0][k][c] = *(const float4*)(Bw + (size_t)k * ldb + n0 + c);
  }
#pragma unroll
  for (int j = 0; j < 4; ++j) {
    int kl = p * 16 + j * 4;
    float4 gg = *(const float4*)(g + kl);
    float4 bb = *(const float4*)(b + kl);
    As[0][kl + 0][r] = v[j].x * gg.x + bb.x;
    As[0][kl + 1][r] = v[j].y * gg.y + bb.y;
    As[0][kl + 2][r] = v[j].z * gg.z + bb.z;
    As[0][kl + 3][r] = v[j].w * gg.w + bb.w;
  }
  __syncthreads();
  for (int c = 0; c < 4; ++c) {
    int cur = c & 1;
    float4 breg[8];
    if (c < 3) {                   // issue next chunk's B loads (in flight over compute)
      int kb = (c + 1) * 64;
#pragma unroll
      for (int i = 0; i < 8; ++i) {
        int idx = tid + 128 * i;
        int k = idx >> 4, cc = (idx & 15) << 2;
        breg[i] = *(const float4*)(Bw + (size_t)(kb + k) * ldb + n0 + cc);
      }
    }
    gemm_chunk(As[cur], Bs[cur], acc);
    if (c < 3) {
      int nxt = cur ^ 1;
      int kb = (c + 1) * 64;
#pragma unroll
      for (int i = 0; i < 8; ++i) {
        int idx = tid + 128 * i;
        int k = idx >> 4, cc = (idx & 15) << 2;
        *(float4*)&Bs[nxt][k][cc] = breg[i];
      }
#pragma unroll
      for (int j = 0; j < 4; ++j) {
        int kl = p * 16 + j * 4;
        float4 gg = *(const float4*)(g + kb + kl);
        float4 bb = *(const float4*)(b + kb + kl);
        float4 vv = v[(c + 1) * 4 + j];
        As[nxt][kl + 0][r] = vv.x * gg.x + bb.x;
        As[nxt][kl + 1][r] = vv.y * gg.y + bb.y;
        As[nxt][kl + 2][r] = vv.z * gg.z + bb.z;
        As[nxt][kl + 3][r] = vv.w * gg.w + bb.w;
      }
      __syncthreads();
    }
  }
}

// A loaded straight from global (no LN). B base may be pre-offset; k local 0..255.
__device__ __forceinline__ void gemm_copy(
    const float* __restrict__ A, int lda, int kbeg,
    const float* __restrict__ Bw, int ldb, int m0, int n0,
    float (*__restrict__ As)[64][36], float (*__restrict__ Bs)[64][64],
    float acc[4][4])
{
  int tid = threadIdx.x;
  int r = tid >> 2, p = tid & 3;
  const float* arow = A + (size_t)(m0 + r) * lda + kbeg;
  // prologue: chunk 0 direct
#pragma unroll
  for (int i = 0; i < 8; ++i) {
    int idx = tid + 128 * i;
    int k = idx >> 4, c = (idx & 15) << 2;
    *(float4*)&Bs[0][k][c] = *(const float4*)(Bw + (size_t)k * ldb + n0 + c);
  }
#pragma unroll
  for (int j = 0; j < 4; ++j) {
    int kl = p * 16 + j * 4;
    float4 vv = *(const float4*)(arow + kl);
    As[0][kl + 0][r] = vv.x; As[0][kl + 1][r] = vv.y;
    As[0][kl + 2][r] = vv.z; As[0][kl + 3][r] = vv.w;
  }
  __syncthreads();
  for (int c = 0; c < 4; ++c) {
    int cur = c & 1;
    float4 breg[8]; float4 areg[4];
    if (c < 3) {
      int kb = (c + 1) * 64;
#pragma unroll
      for (int i = 0; i < 8; ++i) {
        int idx = tid + 128 * i;
        int k = idx >> 4, cc = (idx & 15) << 2;
        breg[i] = *(const float4*)(Bw + (size_t)(kb + k) * ldb + n0 + cc);
      }
#pragma unroll
      for (int j = 0; j < 4; ++j) areg[j] = *(const float4*)(arow + kb + p * 16 + j * 4);
    }
    gemm_chunk(As[cur], Bs[cur], acc);
    if (c < 3) {
      int nxt = cur ^ 1;
#pragma unroll
      for (int i = 0; i < 8; ++i) {
        int idx = tid + 128 * i;
        int k = idx >> 4, cc = (idx & 15) << 2;
        *(float4*)&Bs[nxt][k][cc] = breg[i];
      }
#pragma unroll
      for (int j = 0; j < 4; ++j) {
        int kl = p * 16 + j * 4;
        As[nxt][kl + 0][r] = areg[j].x; As[nxt][kl + 1][r] = areg[j].y;
        As[nxt][kl + 2][r] = areg[j].z; As[nxt][kl + 3][r] = areg[j].w;
      }
      __syncthreads();
    }
  }
}

// ---------- QKV with fused LayerNorm: grid (4,16,3) x 128 ----------
__global__ __launch_bounds__(128) void qkv_kernel(
    const float* __restrict__ srcin, const float* __restrict__ tgt,
    const float* __restrict__ ln1g, const float* __restrict__ ln1b,
    const float* __restrict__ lntg, const float* __restrict__ lntb,
    const float* __restrict__ wq, const float* __restrict__ wk, const float* __restrict__ wv,
    const float* __restrict__ bq, const float* __restrict__ bk, const float* __restrict__ bv,
    float* __restrict__ Qb, float* __restrict__ Kb, float* __restrict__ Vb)
{
  __shared__ __align__(16) float As[2][64][36];
  __shared__ __align__(16) float Bs[2][64][64];
  int z = blockIdx.z;
  int m0 = blockIdx.y * 32, n0 = blockIdx.x * 64;
  const float* Bw = (z == 0) ? wq : (z == 1) ? wk : wv;
  float acc[4][4] = {};
  if (z == 0) gemm_ln(srcin, ln1g, ln1b, Bw, DMODEL, m0, n0, As, Bs, acc);
  else        gemm_ln(tgt, lntg, lntb, Bw, DMODEL, m0, n0, As, Bs, acc);
  const float* bias = (z == 0) ? bq : (z == 1) ? bk : bv;
  int tid = threadIdx.x, tx = tid & 15, ty = tid >> 4;
  int c0 = n0 + tx * 4;
  float4 bias4 = *(const float4*)(bias + c0);
  const float scale = 0.1767766952966369f;  // 1/sqrt(32)
#pragma unroll
  for (int i = 0; i < 4; ++i) {
    int m = m0 + ty * 4 + i;
    float4 r;
    r.x = acc[i][0] + bias4.x;
    r.y = acc[i][1] + bias4.y;
    r.z = acc[i][2] + bias4.z;
    r.w = acc[i][3] + bias4.w;
    if (z == 0) {
      r.x *= scale; r.y *= scale; r.z *= scale; r.w *= scale;
      *(float4*)&Qb[m * DMODEL + c0] = r;
    } else {
      int b = m >> 8, t = m & 255, h = c0 >> 5, d0 = c0 & 31;
      float* dst = ((z == 1) ? Kb : Vb) + (size_t)(b * NH + h) * 8192 + t * DH + d0;
      *(float4*)dst = r;
    }
  }
}

// ---------- wo GEMM + residual (src + bo) : grid (4,16) ----------
__global__ __launch_bounds__(128) void wo_kernel(
    const float* __restrict__ AO, const float* __restrict__ wo,
    const float* __restrict__ srcin, const float* __restrict__ bo,
    float* __restrict__ X)
{
  __shared__ __align__(16) float As[2][64][36];
  __shared__ __align__(16) float Bs[2][64][64];
  int m0 = blockIdx.y * 32, n0 = blockIdx.x * 64;
  float acc[4][4] = {};
  gemm_copy(AO, DMODEL, 0, wo, DMODEL, m0, n0, As, Bs, acc);
  int tid = threadIdx.x, tx = tid & 15, ty = tid >> 4;
  int c0 = n0 + tx * 4;
  float4 bov = *(const float4*)(bo + c0);
#pragma unroll
  for (int i = 0; i < 4; ++i) {
    int m = m0 + ty * 4 + i;
    float4 sv = *(const float4*)(srcin + (size_t)m * DMODEL + c0);
    float4 r;
    r.x = sv.x + bov.x + acc[i][0];
    r.y = sv.y + bov.y + acc[i][1];
    r.z = sv.z + bov.z + acc[i][2];
    r.w = sv.w + bov.w + acc[i][3];
    *(float4*)&X[(size_t)m * DMODEL + c0] = r;
  }
}

// ---------- FF1 + fused LN2 + ReLU; x==0 blocks write out-init ----------
__global__ __launch_bounds__(128) void ff1_kernel(
    const float* __restrict__ X, const float* __restrict__ ln2g, const float* __restrict__ ln2b,
    const float* __restrict__ w1, const float* __restrict__ b1,
    const float* __restrict__ b2, const int* __restrict__ smask,
    float* __restrict__ H1, float* __restrict__ outb)
{
  __shared__ __align__(16) float As[2][64][36];
  __shared__ __align__(16) float Bs[2][64][64];
  int m0 = blockIdx.y * 32, n0 = blockIdx.x * 64;
  if (blockIdx.x == 0) {   // out-init = mask * (X + b2)
    int tid = threadIdx.x;
    int r = tid >> 2, pq = tid & 3;
    int m = m0 + r;
    float mm = (smask[m] != 0) ? 0.0f : 1.0f;
#pragma unroll
    for (int j = 0; j < 4; ++j) {
      float4 xv  = *(const float4*)(X  + (size_t)m * DMODEL + pq * 64 + j * 16);
      float4 b2v = *(const float4*)(b2 + pq * 64 + j * 16);
      float4 o;
      o.x = mm * (xv.x + b2v.x); o.y = mm * (xv.y + b2v.y);
      o.z = mm * (xv.z + b2v.z); o.w = mm * (xv.w + b2v.w);
      *(float4*)(outb + (size_t)m * DMODEL + pq * 64 + j * 16) = o;
      float4 xv2  = *(const float4*)(X  + (size_t)m * DMODEL + pq * 64 + j * 16 + 4);
      float4 b2v2 = *(const float4*)(b2 + pq * 64 + j * 16 + 4);
      float4 o2;
      o2.x = mm * (xv2.x + b2v2.x); o2.y = mm * (xv2.y + b2v2.y);
      o2.z = mm * (xv2.z + b2v2.z); o2.w = mm * (xv2.w + b2v2.w);
      *(float4*)(outb + (size_t)m * DMODEL + pq * 64 + j * 16 + 4) = o2;
      float4 xv3  = *(const float4*)(X  + (size_t)m * DMODEL + pq * 64 + j * 16 + 8);
      float4 b2v3 = *(const float4*)(b2 + pq * 64 + j * 16 + 8);
      float4 o3;
      o3.x = mm * (xv3.x + b2v3.x); o3.y = mm * (xv3.y + b2v3.y);
      o3.z = mm * (xv3.z + b2v3.z); o3.w = mm * (xv3.w + b2v3.w);
      *(float4*)(outb + (size_t)m * DMODEL + pq * 64 + j * 16 + 8) = o3;
      float4 xv4  = *(const float4*)(X  + (size_t)m * DMODEL + pq * 64 + j * 16 + 12);
      float4 b2v4 = *(const float4*)(b2 + pq * 64 + j * 16 + 12);
      float4 o4;
      o4.x = mm * (xv4.x + b2v4.x); o4.y = mm * (xv4.y + b2v4.y);
      o4.z = mm * (xv4.z + b2v4.z); o4.w = mm * (xv4.w + b2v4.w);
      *(float4*)(outb + (size_t)m * DMODEL + pq * 64 + j * 16 + 12) = o4;
    }
  }
  float acc[4][4] = {};
  gemm_ln(X, ln2g, ln2b, w1, 1024, m0, n0, As, Bs, acc);
  int tid = threadIdx.x, tx = tid & 15, ty = tid >> 4;
  int c0 = n0 + tx * 4;
  float4 b1v = *(const float4*)(b1 + c0);
#pragma unroll
  for (int i = 0; i < 4; ++i) {
    int m = m0 + ty * 4 + i;
    float4 r;
    r.x = fmaxf(acc[i][0] + b1v.x, 0.0f);
    r.y = fmaxf(acc[i][1] + b1v.y, 0.0f);
    r.z = fmaxf(acc[i][2] + b1v.z, 0.0f);
    r.w = fmaxf(acc[i][3] + b1v.w, 0.0f);
    *(float4*)&H1[(size_t)m * 1024 + c0] = r;
  }
}

// ---------- FF2 split-K=4, masked atomic accumulate : grid (4,16,4) ----------
__global__ __launch_bounds__(128) void ff2_kernel(
    const float* __restrict__ H1, const float* __restrict__ w2,
    const int* __restrict__ smask, float* __restrict__ outb)
{
  __shared__ __align__(16) float As[2][64][36];
  __shared__ __align__(16) float Bs[2][64][64];
  int m0 = blockIdx.y * 32, n0 = blockIdx.x * 64;
  int kbeg = blockIdx.z * 256;
  float acc[4][4] = {};
  gemm_copy(H1, 1024, kbeg, w2 + (size_t)kbeg * DMODEL, DMODEL, m0, n0, As, Bs, acc);
  int tid = threadIdx.x, tx = tid & 15, ty = tid >> 4;
  int c0 = n0 + tx * 4;
#pragma unroll
  for (int i = 0; i < 4; ++i) {
    int m = m0 + ty * 4 + i;
    if (smask[m] == 0) {
      atomicAdd(&outb[(size_t)m * DMODEL + c0 + 0], acc[i][0]);
      atomicAdd(&outb[(size_t)m * DMODEL + c0 + 1], acc[i][1]);
      atomicAdd(&outb[(size_t)m * DMODEL + c0 + 2], acc[i][2]);
      atomicAdd(&outb[(size_t)m * DMODEL + c0 + 3], acc[i][3]);
    }
  }
}

// ---------- attention: unchanged from verified version ----------
__global__ __launch_bounds__(256) void attn_kernel(
    const float* __restrict__ Qb, const float* __restrict__ Kb, const float* __restrict__ Vb,
    const float* __restrict__ rpe, const int* __restrict__ tmask,
    const float* __restrict__ wrl, const float* __restrict__ brl,
    float* __restrict__ AO)
{
  __shared__ float Ks[256][32];
  __shared__ float Vt[32][260];
  __shared__ float ps[4][256];
  __shared__ float qs[16][32];
  __shared__ float wks[5][32];
  __shared__ float wvs[5][32];
  int bid = blockIdx.x;
  int b = bid >> 7, h = (bid >> 4) & 7, s0 = (bid & 15) << 4;
  int tid = threadIdx.x;
  const float* Kp = Kb + (size_t)(b * NH + h) * 8192;
  const float* Vp = Vb + (size_t)(b * NH + h) * 8192;
  {
    int t = tid;
    const float4* kr = (const float4*)(Kp + t * DH);
    const float4* vr = (const float4*)(Vp + t * DH);
    int sw = t & 7;
#pragma unroll
    for (int c = 0; c < 8; ++c) {
      float4 k4 = kr[c];
      *(float4*)&Ks[t][(c ^ sw) * 4] = k4;
    }
#pragma unroll
    for (int c = 0; c < 8; ++c) {
      float4 v4 = vr[c];
      Vt[c*4+0][t] = v4.x; Vt[c*4+1][t] = v4.y; Vt[c*4+2][t] = v4.z; Vt[c*4+3][t] = v4.w;
    }
  }
  if (tid < 160) {
    int j = tid >> 5, d = tid & 31;
    wks[j][d] = (j < 4) ? wrl[j * 512 + h * DH + d]       : brl[h * DH + d];
    wvs[j][d] = (j < 4) ? wrl[j * 512 + 256 + h * DH + d] : brl[256 + h * DH + d];
  }
  if (tid >= 128) {
    int u = tid - 128;
    int rr = u >> 3, cc = u & 7;
    *(float4*)&qs[rr][cc*4] =
        *(const float4*)&Qb[(b * 256 + s0 + rr) * DMODEL + h * DH + cc * 4];
  }
  __syncthreads();

  int w = tid >> 6, lane = tid & 63;
  int msk[4];
#pragma unroll
  for (int it = 0; it < 4; ++it) msk[it] = tmask[b * 256 + it * 64 + lane];

  for (int i = 0; i < 4; ++i) {
    int sl = w * 4 + i;
    int s = s0 + sl;
    float4 q4[8];
#pragma unroll
    for (int c = 0; c < 8; ++c) q4[c] = *(const float4*)&qs[sl][c * 4];
    float qw[4]; float qbr = 0.0f;
#pragma unroll
    for (int j = 0; j < 4; ++j) {
      float t0 = 0;
#pragma unroll
      for (int c = 0; c < 8; ++c) {
        float4 wv4 = *(const float4*)&wks[j][c * 4];
        t0 += q4[c].x*wv4.x + q4[c].y*wv4.y + q4[c].z*wv4.z + q4[c].w*wv4.w;
      }
      qw[j] = t0;
    }
#pragma unroll
    for (int c = 0; c < 8; ++c) {
      float4 wv4 = *(const float4*)&wks[4][c * 4];
      qbr += q4[c].x*wv4.x + q4[c].y*wv4.y + q4[c].z*wv4.z + q4[c].w*wv4.w;
    }
    const float4* rp4 = (const float4*)(rpe + (size_t)(b * 256 + s) * 1024);
    float sc[4]; float4 rr[4];
#pragma unroll
    for (int it = 0; it < 4; ++it) {
      int t = it * 64 + lane;
      int sw = t & 7;
      float sv = 0;
#pragma unroll
      for (int c = 0; c < 8; ++c) {
        float4 k4 = *(const float4*)&Ks[t][(c ^ sw) * 4];
        sv = fmaf(q4[c].x, k4.x, sv); sv = fmaf(q4[c].y, k4.y, sv);
        sv = fmaf(q4[c].z, k4.z, sv); sv = fmaf(q4[c].w, k4.w, sv);
      }
      float4 rv = rp4[t];
      rr[it] = rv;
      sv += rv.x*qw[0] + rv.y*qw[1] + rv.z*qw[2] + rv.w*qw[3] + qbr;
      if (msk[it] != 0) sv = NEG_INF;
      sc[it] = sv;
    }
    float mval = fmaxf(fmaxf(sc[0], sc[1]), fmaxf(sc[2], sc[3]));
#pragma unroll
    for (int off = 32; off >= 1; off >>= 1) mval = fmaxf(mval, __shfl_xor(mval, off));
    float p[4], lsum = 0;
#pragma unroll
    for (int it = 0; it < 4; ++it) { p[it] = __expf(sc[it] - mval); lsum += p[it]; }
    float wj0 = 0, wj1 = 0, wj2 = 0, wj3 = 0;
#pragma unroll
    for (int it = 0; it < 4; ++it) {
      wj0 = fmaf(p[it], rr[it].x, wj0);
      wj1 = fmaf(p[it], rr[it].y, wj1);
      wj2 = fmaf(p[it], rr[it].z, wj2);
      wj3 = fmaf(p[it], rr[it].w, wj3);
    }
#pragma unroll
    for (int off = 32; off >= 1; off >>= 1) {
      lsum += __shfl_xor(lsum, off);
      wj0 += __shfl_xor(wj0, off);
      wj1 += __shfl_xor(wj1, off);
      wj2 += __shfl_xor(wj2, off);
      wj3 += __shfl_xor(wj3, off);
    }
#pragma unroll
    for (int it = 0; it < 4; ++it) ps[w][it * 64 + lane] = p[it];
    int g = lane >> 5, d = lane & 31;
    float o = 0;
#pragma unroll
    for (int n = 0; n < 32; ++n) {
      int t = g * 128 + n * 4;
      float4 p4 = *(const float4*)&ps[w][t];
      float4 v4 = *(const float4*)&Vt[d][t];
      o += p4.x*v4.x + p4.y*v4.y + p4.z*v4.z + p4.w*v4.w;
    }
    o += __shfl_xor(o, 32);
    float corr = wj0 * wvs[0][d] + wj1 * wvs[1][d] + wj2 * wvs[2][d] + wj3 * wvs[3][d];
    float oval = (o + corr) / lsum + wvs[4][d];
    if (lane < 32) AO[(b * 256 + s) * DMODEL + h * DH + d] = oval;
  }
}

extern "C" void kernel_launch(void* const* d_in, const int* in_sizes, int n_in,
                              void* d_out, int out_size, void* d_ws, size_t ws_size,
                              hipStream_t stream)
{
  const float* src  = (const float*)d_in[0];
  const float* tgt  = (const float*)d_in[1];
  const float* rpe  = (const float*)d_in[2];
  const int*   smask = (const int*)d_in[3];
  const int*   tmask = (const int*)d_in[4];
  const float* ln1g = (const float*)d_in[5];
  const float* ln1b = (const float*)d_in[6];
  const float* lntg = (const float*)d_in[7];
  const float* lntb = (const float*)d_in[8];
  const float* ln2g = (const float*)d_in[9];
  const float* ln2b = (const float*)d_in[10];
  const float* wq = (const float*)d_in[11];
  const float* bq = (const float*)d_in[12];
  const float* wk = (const float*)d_in[13];
  const float* bk = (const float*)d_in[14];
  const float* wv = (const float*)d_in[15];
  const float* bv = (const float*)d_in[16];
  const float* wo = (const float*)d_in[17];
  const float* bo = (const float*)d_in[18];
  const float* wr = (const float*)d_in[19];
  const float* br = (const float*)d_in[20];
  const float* w1 = (const float*)d_in[21];
  const float* b1 = (const float*)d_in[22];
  const float* w2 = (const float*)d_in[23];
  const float* b2 = (const float*)d_in[24];

  float* w    = (float*)d_ws;
  float* Qb   = w;
  float* Kb   = w + 131072;
  float* Vb   = w + 262144;
  float* AO   = w + 393216;
  float* X    = w + 524288;
  float* SRC1 = w + 655360;
  float* H1   = w + 786432;   // 512*1024

  for (int l = 0; l < 2; ++l) {
    const float* srcin = l ? SRC1 : src;
    float* outb = l ? (float*)d_out : SRC1;
    qkv_kernel<<<dim3(4, 16, 3), 128, 0, stream>>>(
        srcin, tgt, ln1g + l*256, ln1b + l*256, lntg + l*256, lntb + l*256,
        wq + l*65536, wk + l*65536, wv + l*65536,
        bq + l*256, bk + l*256, bv + l*256, Qb, Kb, Vb);
    attn_kernel<<<256, 256, 0, stream>>>(Qb, Kb, Vb, rpe, tmask,
                                         wr + l*2048, br + l*512, AO);
    wo_kernel<<<dim3(4, 16), 128, 0, stream>>>(AO, wo + l*65536, srcin, bo + l*256, X);
    ff1_kernel<<<dim3(16, 16), 128, 0, stream>>>(X, ln2g + l*256, ln2b + l*256,
                                                 w1 + l*262144, b1 + l*1024,
                                                 b2 + l*256, smask, H1, outb);
    ff2_kernel<<<dim3(4, 16, 4), 128, 0, stream>>>(H1, w2 + l*262144, smask, outb);
  }
}